// Round 12
// baseline (903.955 us; speedup 1.0000x reference)
//
#include <hip/hip_runtime.h>
#include <hip/hip_bf16.h>

#define D_IN 256
#define DM   1024
#define HD   2048
#define NE   8
#define NTOK 16384

typedef __attribute__((ext_vector_type(8))) short short8;
typedef __attribute__((ext_vector_type(4))) float f32x4;
typedef unsigned int uint;

// ---- meta layout (uint indices) ----
#define MT_TOFF1 0      // [64][8]
#define MT_TOFF2 512    // [64][16]
#define MT_CNT1  1536   // [8][8]
#define MT_P1    1600   // [8][8]    roundup256(cnt1)  (ffn1 BM=256)
#define MT_OFF1  1664   // [8][8]
#define MT_CNT2  1728   // [8][16]   [slot0 e0..7 | slot1 e0..7]
#define MT_PCNT2 1856   // [8][16]   roundup128(cnt2)
#define MT_TOTAL 1984

__device__ inline ushort f2bf(float v){
  __hip_bfloat16 b = __float2bfloat16(v);
  return *reinterpret_cast<ushort*>(&b);
}
__device__ inline float bf2f(ushort u){
  __hip_bfloat16 b = *reinterpret_cast<__hip_bfloat16*>(&u);
  return __bfloat162float(b);
}

// gelu tanh-approx via identity 0.5*(1+tanh(u)) = sigmoid(2u)
__device__ inline float gelu_fast(float x){
  float u = 0.7978845608028654f * x * (1.0f + 0.044715f*x*x);
  return x / (1.0f + __expf(-2.0f*u));
}

__device__ inline void gload16(const void* g, void* l){
  __builtin_amdgcn_global_load_lds(
      (const __attribute__((address_space(1))) void*)g,
      (__attribute__((address_space(3))) void*)l, 16, 0, 0);
}

// LDS bank swizzle (both sides, involution): chunk c (16B) of row r stored at
// position c ^ ((r>>1)&3) within the row's 64B; stage sources the inverse-
// permuted global chunk so gload_lds dests stay linear. Verified: conflicts=0 (r11).

// ---------- transpose [R][C] f32 -> [C][R] bf16 (per expert, blockIdx.z) ----------
__global__ __launch_bounds__(256) void transpose_bf16_kernel(
    const float* __restrict__ src, ushort* __restrict__ dst, int R, int C)
{
  __shared__ float tile[32][33];
  int e = blockIdx.z;
  src += (size_t)e*R*C; dst += (size_t)e*R*C;
  int c0 = blockIdx.x*32, r0 = blockIdx.y*32;
  int tx = threadIdx.x & 31, ty = threadIdx.x >> 5;
  #pragma unroll
  for (int rr = ty; rr < 32; rr += 8)
    tile[rr][tx] = src[(size_t)(r0+rr)*C + c0+tx];
  __syncthreads();
  #pragma unroll
  for (int rr = ty; rr < 32; rr += 8)
    dst[(size_t)(c0+rr)*R + r0+tx] = f2bf(tile[tx][rr]);
}

// ---------- split x[N][256] f32 -> xs3[N][768] bf16 (hi|mid|lo 256-blocks) ----------
__global__ __launch_bounds__(256) void split_x_kernel(
    const float* __restrict__ x, ushort* __restrict__ xs3)
{
  int g = blockIdx.x*256 + threadIdx.x;     // one thread = 4 consecutive floats
  int e0 = g*4;
  int row = e0 >> 8, col = e0 & 255;
  f32x4 v = *(const f32x4*)(x + (size_t)row*D_IN + col);
  ushort4 hi, mi, lo;
  #pragma unroll
  for (int i=0;i<4;++i){
    float f = v[i];
    ushort h = f2bf(f);       float fh = bf2f(h);
    ushort m = f2bf(f - fh);  float fm = bf2f(m);
    ushort l = f2bf(f - fh - fm);
    ((ushort*)&hi)[i]=h; ((ushort*)&mi)[i]=m; ((ushort*)&lo)[i]=l;
  }
  ushort* base = xs3 + (size_t)row*768 + col;
  *(ushort4*)(base)       = hi;
  *(ushort4*)(base + 256) = mi;
  *(ushort4*)(base + 512) = lo;
}

// ---------- transpose+split w_in[256][1024] f32 -> wt3[1024][768] bf16 ----------
__global__ __launch_bounds__(256) void transpose_split3_kernel(
    const float* __restrict__ src, ushort* __restrict__ dst)
{
  __shared__ float tile[32][33];
  int c0 = blockIdx.x*32, r0 = blockIdx.y*32;
  int tx = threadIdx.x & 31, ty = threadIdx.x >> 5;
  #pragma unroll
  for (int rr = ty; rr < 32; rr += 8)
    tile[rr][tx] = src[(size_t)(r0+rr)*DM + c0+tx];
  __syncthreads();
  #pragma unroll
  for (int rr = ty; rr < 32; rr += 8){
    float f = tile[tx][rr];   // src[r0+tx][c0+rr]
    ushort h = f2bf(f);       float fh = bf2f(h);
    ushort m = f2bf(f - fh);  float fm = bf2f(m);
    ushort l = f2bf(f - fh - fm);
    ushort* d = dst + (size_t)(c0+rr)*768 + r0 + tx;
    d[0]   = h;
    d[256] = m;
    d[512] = l;
  }
}

// ---------- w_gate[1024][8] -> wgt[8][1024] ----------
__global__ __launch_bounds__(256) void wgate_t_kernel(
    const float* __restrict__ w_gate, float* __restrict__ wgt)
{
  int e = blockIdx.x;
  for (int j = threadIdx.x; j < DM; j += 256)
    wgt[(size_t)e*DM + j] = w_gate[(size_t)j*NE + e];
}

// ---------- router GEMM: y = x @ w_in + b_in via bf16x3 (6 terms, K=6*256) ----------
// 3-deep dbuf pipeline + bank-swizzled LDS + setprio around MFMA.
__global__ __launch_bounds__(256) void gemm_router(
    const ushort* __restrict__ A,    // [NTOK][768]
    const ushort* __restrict__ BT,   // [DM][768]
    const float* __restrict__ b_in,
    float* __restrict__ y)           // [NTOK][DM]
{
  __shared__ ushort As[3][128*32];
  __shared__ ushort Bs[3][128*32];
  const int tid = threadIdx.x;
  const int w = tid>>6, l = tid&63;
  const int wm = w>>1, wn = w&1;
  const int bm0 = blockIdx.y*128, bn0 = blockIdx.x*128;
  const int lr = l&15, lk = l>>4;
  const int rsub = l>>2;
  const int csub = ((l&3) ^ ((l>>3)&3)) * 8;   // swizzled source chunk

  const ushort* ag[2]; const ushort* bg[2];
  int aslot[2];
  #pragma unroll
  for (int i=0;i<2;++i){
    int ra = bm0 + w*32 + i*16 + rsub;
    int rb = bn0 + w*32 + i*16 + rsub;
    ag[i] = A  + (size_t)ra*768 + csub;
    bg[i] = BT + (size_t)rb*768 + csub;
    aslot[i] = (w*32 + i*16)*32;
  }

  const int pOffT[6] = {0,256,0,256,512,0};
  const int qOffT[6] = {0,0,256,256,0,512};
  auto stage = [&](int db, int t){
    int pOff = pOffT[t>>3] + (t&7)*32;
    int qOff = qOffT[t>>3] + (t&7)*32;
    #pragma unroll
    for (int i=0;i<2;++i){
      gload16(ag[i]+pOff, (ushort*)As[db] + aslot[i]);
      gload16(bg[i]+qOff, (ushort*)Bs[db] + aslot[i]);
    }
  };

  f32x4 acc[4][4] = {};
  const int NK = 48;
  stage(0, 0); stage(1, 1);
  int cur = 0;
  for (int t=0; t<NK; ++t){
    int sb = cur - 1; if (sb < 0) sb = 2;          // == (t+2)%3
    if (t+2 < NK)     { stage(sb, t+2); asm volatile("s_waitcnt vmcnt(8)" ::: "memory"); }
    else if (t+1 < NK){                 asm volatile("s_waitcnt vmcnt(4)" ::: "memory"); }
    else              {                 asm volatile("s_waitcnt vmcnt(0)" ::: "memory"); }
    __builtin_amdgcn_s_barrier();
    short8 af[4], bf[4];
    #pragma unroll
    for (int i=0;i<4;++i)
      af[i] = *(const short8*)(As[cur] + (wm*64 + i*16 + lr)*32 + (lk ^ ((lr>>1)&3))*8);
    #pragma unroll
    for (int j=0;j<4;++j)
      bf[j] = *(const short8*)(Bs[cur] + (wn*64 + j*16 + lr)*32 + (lk ^ ((lr>>1)&3))*8);
    __builtin_amdgcn_s_setprio(1);
    #pragma unroll
    for (int i=0;i<4;++i){
      #pragma unroll
      for (int j=0;j<4;++j)
        acc[i][j] = __builtin_amdgcn_mfma_f32_16x16x32_bf16(af[i], bf[j], acc[i][j], 0, 0, 0);
    }
    __builtin_amdgcn_s_setprio(0);
    __builtin_amdgcn_s_barrier();
    cur = cur + 1; if (cur > 2) cur = 0;
  }

  #pragma unroll
  for (int i=0;i<4;++i){
    #pragma unroll
    for (int j=0;j<4;++j){
      int n = bn0 + wn*64 + j*16 + lr;
      float bn_ = b_in[n];
      #pragma unroll
      for (int r=0;r<4;++r){
        int m = bm0 + wm*64 + i*16 + lk*4 + r;
        y[(size_t)m*DM + n] = acc[i][j][r] + bn_;
      }
    }
  }
}

// ---------- LN + logits + softmax top2 (wave per token), in-place on y ----------
__device__ inline double wredd(double v){
  #pragma unroll
  for (int o=32;o>0;o>>=1) v += __shfl_xor(v, o, 64);
  return v;
}

__global__ __launch_bounds__(256) void ln_router_kernel(
    const float* __restrict__ g_in, const float* __restrict__ beta_in,
    const float* __restrict__ wgt,
    ushort* __restrict__ hbf, float* __restrict__ resid,
    float* __restrict__ gates, int* __restrict__ selmask)
{
  int tok = blockIdx.x*4 + (threadIdx.x>>6);
  int l = threadIdx.x & 63;
  float* row = resid + (size_t)tok*DM;
  float u[16];
  double s=0.0, q=0.0;
  #pragma unroll
  for (int r=0;r<16;++r){ u[r]=row[l+64*r]; s+=u[r]; q+=(double)u[r]*u[r]; }
  s = wredd(s); q = wredd(q);
  double mean = s*(1.0/1024.0);
  double var  = q*(1.0/1024.0) - mean*mean;
  double rstd = 1.0/sqrt(var + 1e-5);

  double lg[NE];
  #pragma unroll
  for (int e=0;e<NE;++e) lg[e]=0.0;
  float hv[16];
  #pragma unroll
  for (int r=0;r<16;++r){
    int j = l + 64*r;
    double v = ((double)u[r]-mean)*rstd*(double)g_in[j] + (double)beta_in[j];
    hv[r] = (float)v;
    #pragma unroll
    for (int e=0;e<NE;++e) lg[e] += v*(double)wgt[(size_t)e*DM + j];
  }
  #pragma unroll
  for (int r=0;r<16;++r){
    int j = l + 64*r;
    row[j] = hv[r];
    hbf[(size_t)tok*DM + j] = f2bf(hv[r]);
  }
  #pragma unroll
  for (int e=0;e<NE;++e) lg[e] = wredd(lg[e]);

  if (l==0){
    double mx = lg[0];
    #pragma unroll
    for (int e=1;e<NE;++e) mx = lg[e]>mx ? lg[e] : mx;
    double p[NE]; double sum=0.0;
    #pragma unroll
    for (int e=0;e<NE;++e){ p[e]=exp(lg[e]-mx); sum+=p[e]; }
    #pragma unroll
    for (int e=0;e<NE;++e) p[e]/=sum;
    int i1=0;
    for (int e=1;e<NE;++e) if (p[e]>p[i1]) i1=e;
    int i2=-1;
    for (int e=0;e<NE;++e){ if (e==i1) continue; if (i2<0 || p[e]>p[i2]) i2=e; }
    double denom = p[i1]+p[i2]+1e-9;
    float g[NE];
    #pragma unroll
    for (int e=0;e<NE;++e) g[e]=0.f;
    g[i1]=(float)(p[i1]/denom);
    g[i2]=(float)(p[i2]/denom);
    #pragma unroll
    for (int e=0;e<NE;++e) gates[(size_t)tok*NE+e]=g[e];
    selmask[tok] = (1<<i1)|(1<<i2);
  }
}

// ---------- builders ----------
__global__ __launch_bounds__(256) void builder_count(
    const int* __restrict__ selmask, uint* __restrict__ bc1, uint* __restrict__ bc2)
{
  __shared__ uint c1[8], c2s[16];
  int b = blockIdx.x, tid = threadIdx.x;
  if (tid<8) c1[tid]=0;
  if (tid<16) c2s[tid]=0;
  __syncthreads();
  int m = selmask[b*256+tid];
  int ea = __ffs(m)-1, eb = 31-__clz(m);
  atomicAdd(&c1[ea],1u); atomicAdd(&c1[eb],1u);
  atomicAdd(&c2s[ea],1u); atomicAdd(&c2s[8+eb],1u);
  __syncthreads();
  if (tid<8) bc1[b*8+tid]=c1[tid];
  if (tid<16) bc2[b*16+tid]=c2s[tid];
}

__global__ __launch_bounds__(256) void builder_scan(
    const uint* __restrict__ bc1, const uint* __restrict__ bc2,
    uint* __restrict__ meta, int nch, int TPC)
{
  int tid = threadIdx.x;
  int c = tid/24, k = tid%24;
  if (c < nch){
    if (k < 8){
      uint run=0;
      for (int b=c*TPC; b<(c+1)*TPC; ++b){ meta[MT_TOFF1 + b*8 + k] = run; run += bc1[b*8+k]; }
      meta[MT_CNT1 + c*8 + k] = run;
    } else {
      int k2 = k-8;
      uint run=0;
      for (int b=c*TPC; b<(c+1)*TPC; ++b){ meta[MT_TOFF2 + b*16 + k2] = run; run += bc2[b*16+k2]; }
      meta[MT_CNT2 + c*16 + k2] = run;
      meta[MT_PCNT2 + c*16 + k2] = ((run + 127u)/128u)*128u;
    }
  }
  __syncthreads();
  if (tid < nch){
    uint off=0;
    for (int e=0;e<8;++e){
      uint cn = meta[MT_CNT1 + tid*8 + e];
      uint p = ((cn+255u)/256u)*256u;     // 256-pad (ffn1 BM=256)
      meta[MT_P1 + tid*8 + e] = p;
      meta[MT_OFF1 + tid*8 + e] = off;
      off += p;
    }
  }
}

__device__ inline int exclscan256(int v, int* sc, int tid){
  sc[tid]=v; __syncthreads();
  #pragma unroll
  for (int o=1;o<256;o<<=1){
    int x = (tid>=o) ? sc[tid-o] : 0;
    __syncthreads();
    sc[tid]+=x;
    __syncthreads();
  }
  int incl = sc[tid]; __syncthreads();
  return incl - v;
}

// L1 list per (chunk, expert): slot0 tokens first [0,cnt2a), then slot1 [cnt2a,cnt1)
__global__ __launch_bounds__(256) void builder_fill(
    const int* __restrict__ selmask, const uint* __restrict__ meta,
    int* __restrict__ ids1, int CH)
{
  __shared__ int sc[256];
  int b = blockIdx.x, tid = threadIdx.x;
  int t = b*256 + tid;
  int c = t / CH;
  int m = selmask[t];
  int ea = __ffs(m)-1, eb = 31-__clz(m);
  int ja=0, jb=0;
  for (int e=0;e<8;++e){
    int r0 = exclscan256((ea==e)?1:0, sc, tid);
    if (ea==e) ja = r0;
    int r1 = exclscan256((eb==e)?1:0, sc, tid);
    if (eb==e) jb = r1;
  }
  {
    uint j    = meta[MT_TOFF2 + b*16 + ea] + (uint)ja;       // slot0 position
    ids1[(c*8+ea)*CH + j] = t;
  }
  {
    uint j    = meta[MT_TOFF2 + b*16 + 8 + eb] + (uint)jb;   // slot1 position
    uint pos1 = meta[MT_CNT2 + c*16 + eb] + j;
    ids1[(c*8+eb)*CH + pos1] = t;
  }
}

// ---------- FFN-1: gather-GEMM, BM=256 x BN=128, 512 thr, 3-deep dbuf, swizzle ----------
// 8 waves: wm = wid>>1 (0..3) rows, wn = wid&1 (0..1) cols; 72KB LDS -> 2 blk/CU
// = 16 waves/CU (4/SIMD, up from 3). Stage = 3 loads/thread/tile -> vmcnt 6/3/0.
__global__ __launch_bounds__(512) void gemm_ffn1(
    const ushort* __restrict__ Abase,   // hbf
    const ushort* __restrict__ BT,      // w1t [E][HD][DM]
    const int*   __restrict__ rows,     // ids1 + c*8*CH
    const uint*  __restrict__ pcnt,     // P1 (256-padded)
    const uint*  __restrict__ off1,
    const float* __restrict__ bias,     // b1
    ushort* __restrict__ t1,
    int K, int N, int CH)
{
  const int e = blockIdx.z;
  const int bm0 = blockIdx.y*256;
  if ((uint)bm0 >= pcnt[e]) return;
  const int bn0 = blockIdx.x*128;

  __shared__ ushort As[3][256*32];
  __shared__ ushort Bs[3][128*32];
  const int tid = threadIdx.x;
  const int wid = tid>>6, l = tid&63;
  const int wm = wid>>1, wn = wid&1;
  const int lr = l&15, lk = l>>4;

  // stage sources: A pass p: slot idx=p*512+tid -> row=idx>>2, pos=tid&3,
  // source chunk = pos ^ ((row>>1)&3). B: slot idx=tid.
  const ushort* agp[2]; const ushort* bgp;
  #pragma unroll
  for (int pss=0;pss<2;++pss){
    int rowa = (pss*512 + tid)>>2;
    int id = rows[e*CH + bm0 + rowa];
    agp[pss] = Abase + (size_t)id*K + (((tid&3) ^ ((rowa>>1)&3))*8);
  }
  {
    int rowb = tid>>2;
    bgp = BT + (size_t)e*N*K + (size_t)(bn0 + rowb)*K + (((tid&3) ^ ((rowb>>1)&3))*8);
  }

  auto stage = [&](int db, int kt){
    gload16(agp[0]+kt, (ushort*)As[db] + tid*8);
    gload16(agp[1]+kt, (ushort*)As[db] + (512+tid)*8);
    gload16(bgp   +kt, (ushort*)Bs[db] + tid*8);
  };

  f32x4 acc[4][4] = {};
  const int NK = K>>5;
  stage(0, 0); stage(1, 32);
  int cur = 0;
  for (int t=0; t<NK; ++t){
    int sb = cur - 1; if (sb < 0) sb = 2;          // == (t+2)%3
    if (t+2 < NK)     { stage(sb, (t+2)<<5); asm volatile("s_waitcnt vmcnt(6)" ::: "memory"); }
    else if (t+1 < NK){                      asm volatile("s_waitcnt vmcnt(3)" ::: "memory"); }
    else              {                      asm volatile("s_waitcnt vmcnt(0)" ::: "memory"); }
    __builtin_amdgcn_s_barrier();
    short8 af[4], bf[4];
    #pragma unroll
    for (int i=0;i<4;++i){
      int r = wm*64 + i*16 + lr;
      af[i] = *(const short8*)(As[cur] + r*32 + (lk ^ ((r>>1)&3))*8);
    }
    #pragma unroll
    for (int j=0;j<4;++j){
      int rb = wn*64 + j*16 + lr;
      bf[j] = *(const short8*)(Bs[cur] + rb*32 + (lk ^ ((rb>>1)&3))*8);
    }
    __builtin_amdgcn_s_setprio(1);
    #pragma unroll
    for (int i=0;i<4;++i){
      #pragma unroll
      for (int j=0;j<4;++j)
        acc[i][j] = __builtin_amdgcn_mfma_f32_16x16x32_bf16(af[i], bf[j], acc[i][j], 0, 0, 0);
    }
    __builtin_amdgcn_s_setprio(0);
    __builtin_amdgcn_s_barrier();
    cur = cur + 1; if (cur > 2) cur = 0;
  }

  #pragma unroll
  for (int i=0;i<4;++i){
    #pragma unroll
    for (int j=0;j<4;++j){
      int n = bn0 + wn*64 + j*16 + lr;
      float bn_ = bias[(size_t)e*N + n];
      #pragma unroll
      for (int r=0;r<4;++r){
        int mloc = wm*64 + i*16 + lk*4 + r;
        float v = acc[i][j][r] + bn_;
        size_t trow = (size_t)off1[e] + bm0 + mloc;
        t1[trow*N + n] = f2bf(gelu_fast(v));
      }
    }
  }
}

// ---------- FFN-2: DENSE-A slot GEMM + 3-deep dbuf + swizzle (unchanged control) ----------
template<int SLOT>
__global__ __launch_bounds__(256) void gemm_ffn2(
    const ushort* __restrict__ t1,
    const ushort* __restrict__ BT,      // w2t [E][DM][HD]
    const int*   __restrict__ ids1,     // + c*8*CH
    const uint*  __restrict__ cnt2,     // [16] slot0 e0..7 | slot1 e0..7
    const uint*  __restrict__ pcnt2,    // [16] 128-padded
    const uint*  __restrict__ off1,
    const float* __restrict__ bias,     // b2
    const float* __restrict__ gates,
    float* __restrict__ resid,
    int K, int N, int CH)
{
  const int e = blockIdx.z;
  const int bm0 = blockIdx.y*128;
  if ((uint)bm0 >= pcnt2[SLOT*8 + e]) return;
  const uint scnt  = cnt2[SLOT*8 + e];
  const uint start = (SLOT==1) ? cnt2[e] : 0u;
  const int bn0 = blockIdx.x*128;

  __shared__ ushort As[3][128*32];
  __shared__ ushort Bs[3][128*32];
  const int tid = threadIdx.x;
  const int w = tid>>6, l = tid&63;
  const int wm = w>>1, wn = w&1;
  const int lr = l&15, lk = l>>4;
  const int rsub = l>>2;
  const int csub = ((l&3) ^ ((l>>3)&3)) * 8;   // swizzled source chunk

  const ushort* ag[2]; const ushort* bg[2];
  int slot[2];
  #pragma unroll
  for (int i=0;i<2;++i){
    int ra = w*32 + i*16 + rsub;
    size_t arow = (size_t)off1[e] + start + bm0 + ra;   // dense, no gather
    ag[i] = t1 + arow*K + csub;
    int rb = bn0 + w*32 + i*16 + rsub;
    bg[i] = BT + (size_t)e*N*K + (size_t)rb*K + csub;
    slot[i] = (w*32 + i*16)*32;
  }

  auto stage = [&](int db, int kt){
    #pragma unroll
    for (int i=0;i<2;++i){
      gload16(ag[i]+kt, (ushort*)As[db] + slot[i]);
      gload16(bg[i]+kt, (ushort*)Bs[db] + slot[i]);
    }
  };

  f32x4 acc[4][4] = {};
  const int NK = K>>5;
  stage(0, 0); stage(1, 32);
  int cur = 0;
  for (int t=0; t<NK; ++t){
    int sb = cur - 1; if (sb < 0) sb = 2;          // == (t+2)%3
    if (t+2 < NK)     { stage(sb, (t+2)<<5); asm volatile("s_waitcnt vmcnt(8)" ::: "memory"); }
    else if (t+1 < NK){                      asm volatile("s_waitcnt vmcnt(4)" ::: "memory"); }
    else              {                      asm volatile("s_waitcnt vmcnt(0)" ::: "memory"); }
    __builtin_amdgcn_s_barrier();
    short8 af[4], bf[4];
    #pragma unroll
    for (int i=0;i<4;++i)
      af[i] = *(const short8*)(As[cur] + (wm*64 + i*16 + lr)*32 + (lk ^ ((lr>>1)&3))*8);
    #pragma unroll
    for (int j=0;j<4;++j)
      bf[j] = *(const short8*)(Bs[cur] + (wn*64 + j*16 + lr)*32 + (lk ^ ((lr>>1)&3))*8);
    __builtin_amdgcn_s_setprio(1);
    #pragma unroll
    for (int i=0;i<4;++i){
      #pragma unroll
      for (int j=0;j<4;++j)
        acc[i][j] = __builtin_amdgcn_mfma_f32_16x16x32_bf16(af[i], bf[j], acc[i][j], 0, 0, 0);
    }
    __builtin_amdgcn_s_setprio(0);
    __builtin_amdgcn_s_barrier();
    cur = cur + 1; if (cur > 2) cur = 0;
  }

  #pragma unroll
  for (int i=0;i<4;++i){
    #pragma unroll
    for (int j=0;j<4;++j){
      int n = bn0 + wn*64 + j*16 + lr;
      float bn_ = bias[(size_t)e*N + n];
      #pragma unroll
      for (int r=0;r<4;++r){
        int mloc = wm*64 + i*16 + lk*4 + r;
        int mg = bm0 + mloc;
        if ((uint)mg < scnt){
          int tok = ids1[e*CH + (int)start + mg];
          float g = gates[(size_t)tok*NE + e];
          resid[(size_t)tok*N + n] += g*(acc[i][j][r] + bn_);
        }
      }
    }
  }
}

// ---------- final: LN(resid) -> LN -> @w_cls + b_cls (4 tokens/block) ----------
__global__ __launch_bounds__(256) void final_kernel(
    const float* __restrict__ resid,
    const float* __restrict__ g_moe, const float* __restrict__ beta_moe,
    const float* __restrict__ g_out, const float* __restrict__ beta_out,
    const float* __restrict__ w_cls, const float* __restrict__ b_cls,
    float* __restrict__ out)
{
  int tok = blockIdx.x*4 + (threadIdx.x>>6);
  int l = threadIdx.x & 63;
  const float* row = resid + (size_t)tok*DM;
  float u[16];
  double s=0.0,q=0.0;
  #pragma unroll
  for (int r=0;r<16;++r){ u[r]=row[l + 64*r]; s+=u[r]; q+=(double)u[r]*u[r]; }
  s=wredd(s); q=wredd(q);
  double m1 = s*(1.0/1024.0), v1 = q*(1.0/1024.0)-m1*m1;
  double rs1 = 1.0/sqrt(v1+1e-5);
  float tv[16]; double s2=0.0,q2=0.0;
  #pragma unroll
  for (int r=0;r<16;++r){
    int j = l+64*r;
    float vv = (float)((u[r]-m1)*rs1)*g_moe[j] + beta_moe[j];
    tv[r]=vv; s2+=vv; q2+=(double)vv*vv;
  }
  s2=wredd(s2); q2=wredd(q2);
  double m2=s2*(1.0/1024.0), v2=q2*(1.0/1024.0)-m2*m2;
  double rs2=1.0/sqrt(v2+1e-5);
  double p0=0.0,p1=0.0;
  #pragma unroll
  for (int r=0;r<16;++r){
    int j=l+64*r;
    double y=((double)tv[r]-m2)*rs2*(double)g_out[j]+(double)beta_out[j];
    p0+=y*(double)w_cls[j*2]; p1+=y*(double)w_cls[j*2+1];
  }
  p0=wredd(p0); p1=wredd(p1);
  if (l==0){
    out[(size_t)tok*2  ]=(float)(p0+(double)b_cls[0]);
    out[(size_t)tok*2+1]=(float)(p1+(double)b_cls[1]);
  }
}

extern "C" void kernel_launch(void* const* d_in, const int* in_sizes, int n_in,
                              void* d_out, int out_size, void* d_ws, size_t ws_size,
                              hipStream_t stream)
{
  (void)in_sizes; (void)n_in; (void)out_size;
  const float* x       = (const float*)d_in[0];
  const float* w_in    = (const float*)d_in[1];
  const float* b_in    = (const float*)d_in[2];
  const float* g_in    = (const float*)d_in[3];
  const float* beta_in = (const float*)d_in[4];
  const float* w_gate  = (const float*)d_in[5];
  const float* w1      = (const float*)d_in[6];
  const float* b1      = (const float*)d_in[7];
  const float* w2      = (const float*)d_in[8];
  const float* b2      = (const float*)d_in[9];
  const float* g_moe   = (const float*)d_in[10];
  const float* beta_mo = (const float*)d_in[11];
  const float* g_out   = (const float*)d_in[12];
  const float* beta_ou = (const float*)d_in[13];
  const float* w_cls   = (const float*)d_in[14];
  const float* b_cls   = (const float*)d_in[15];
  float* out = (float*)d_out;

  // ---- workspace carve ----
  char* p = (char*)d_ws;
  ushort* w1t   = (ushort*)p; p += (size_t)NE*HD*DM*2;
  ushort* w2t   = (ushort*)p; p += (size_t)NE*DM*HD*2;
  ushort* hbf   = (ushort*)p; p += (size_t)NTOK*DM*2;
  float*  resid = (float*)p;  p += (size_t)NTOK*DM*4;      // also router-GEMM y
  float*  gates = (float*)p;  p += (size_t)NTOK*NE*4;
  int*    selmk = (int*)p;    p += (size_t)NTOK*4;
  int*    ids1  = (int*)p;    p += (size_t)NE*NTOK*4;
  ushort* wt3   = (ushort*)p; p += (size_t)DM*768*2;
  float*  wgt   = (float*)p;  p += (size_t)NE*DM*4;
  uint*   bc1   = (uint*)p;   p += (size_t)64*8*4;
  uint*   bc2   = (uint*)p;   p += (size_t)64*16*4;
  uint*   meta  = (uint*)p;   p += (size_t)MT_TOTAL*4;
  size_t fixed = (size_t)(p - (char*)d_ws);

  const size_t xs3_bytes = (size_t)NTOK*768*2;             // 25.2 MB
  // t1 slack: 8 experts x 255 max pad (256-pad) + dense-A overrun < 2048+256 rows
  size_t t1b1 = ((size_t)2*NTOK        + 2304)*HD*2;
  size_t t1b2 = ((size_t)2*(NTOK/2)    + 2304)*HD*2;
  size_t t1b4 = ((size_t)2*(NTOK/4)    + 2304)*HD*2;
  int nch = 8;
  if      (ws_size >= fixed + (t1b1 > xs3_bytes ? t1b1 : xs3_bytes)) nch = 1;
  else if (ws_size >= fixed + (t1b2 > xs3_bytes ? t1b2 : xs3_bytes)) nch = 2;
  else if (ws_size >= fixed + (t1b4 > xs3_bytes ? t1b4 : xs3_bytes)) nch = 4;
  const int CH  = NTOK/nch;
  const int TPC = CH/256;
  ushort* t1  = (ushort*)p;
  ushort* xs3 = (ushort*)p;       // aliases t1 (dead before t1 written)

  // ---- router path (bf16x3 MFMA emulated-f32) ----
  split_x_kernel<<<dim3(NTOK*D_IN/4/256), 256, 0, stream>>>(x, xs3);
  transpose_split3_kernel<<<dim3(DM/32, D_IN/32), 256, 0, stream>>>(w_in, wt3);
  wgate_t_kernel<<<dim3(NE), 256, 0, stream>>>(w_gate, wgt);
  transpose_bf16_kernel<<<dim3(HD/32, DM/32, NE), 256, 0, stream>>>(w1, w1t, DM, HD);
  transpose_bf16_kernel<<<dim3(DM/32, HD/32, NE), 256, 0, stream>>>(w2, w2t, HD, DM);

  gemm_router<<<dim3(DM/128, NTOK/128), 256, 0, stream>>>(xs3, wt3, b_in, resid);
  ln_router_kernel<<<dim3(NTOK/4), 256, 0, stream>>>(g_in, beta_in, wgt,
                                                     hbf, resid, gates, selmk);

  hipMemsetAsync(ids1, 0, (size_t)NE*NTOK*4, stream);

  builder_count<<<dim3(NTOK/256), 256, 0, stream>>>(selmk, bc1, bc2);
  builder_scan<<<dim3(1), 256, 0, stream>>>(bc1, bc2, meta, nch, TPC);
  builder_fill<<<dim3(NTOK/256), 256, 0, stream>>>(selmk, meta, ids1, CH);

  for (int c = 0; c < nch; ++c) {
    gemm_ffn1<<<dim3(HD/128, CH/256, NE), 512, 0, stream>>>(
        hbf, w1t, ids1 + (size_t)c*8*CH,
        meta+MT_P1+c*8, meta+MT_OFF1+c*8, b1, t1, DM, HD, CH);
    gemm_ffn2<0><<<dim3(DM/128, CH/128, NE), 256, 0, stream>>>(
        t1, w2t, ids1 + (size_t)c*8*CH,
        meta+MT_CNT2+c*16, meta+MT_PCNT2+c*16, meta+MT_OFF1+c*8,
        b2, gates, resid, HD, DM, CH);
    gemm_ffn2<1><<<dim3(DM/128, CH/128, NE), 256, 0, stream>>>(
        t1, w2t, ids1 + (size_t)c*8*CH,
        meta+MT_CNT2+c*16, meta+MT_PCNT2+c*16, meta+MT_OFF1+c*8,
        b2, gates, resid, HD, DM, CH);
  }

  final_kernel<<<dim3(NTOK/4), 256, 0, stream>>>(resid, g_moe, beta_mo, g_out, beta_ou,
                                                 w_cls, b_cls, out);
}

// Round 13
// 892.770 us; speedup vs baseline: 1.0125x; 1.0125x over previous
//
#include <hip/hip_runtime.h>
#include <hip/hip_bf16.h>

#define D_IN 256
#define DM   1024
#define HD   2048
#define NE   8
#define NTOK 16384

typedef __attribute__((ext_vector_type(8))) short short8;
typedef __attribute__((ext_vector_type(4))) float f32x4;
typedef unsigned int uint;

// ---- meta layout (uint indices) ----
#define MT_TOFF1 0      // [64][8]
#define MT_TOFF2 512    // [64][16]
#define MT_CNT1  1536   // [8][8]
#define MT_P1    1600   // [8][8]    roundup128(cnt1)
#define MT_OFF1  1664   // [8][8]
#define MT_CNT2  1728   // [8][16]   [slot0 e0..7 | slot1 e0..7]
#define MT_PCNT2 1856   // [8][16]   roundup128(cnt2)
#define MT_TOTAL 1984

__device__ inline ushort f2bf(float v){
  __hip_bfloat16 b = __float2bfloat16(v);
  return *reinterpret_cast<ushort*>(&b);
}
__device__ inline float bf2f(ushort u){
  __hip_bfloat16 b = *reinterpret_cast<__hip_bfloat16*>(&u);
  return __bfloat162float(b);
}

// gelu tanh-approx via identity 0.5*(1+tanh(u)) = sigmoid(2u)
__device__ inline float gelu_fast(float x){
  float u = 0.7978845608028654f * x * (1.0f + 0.044715f*x*x);
  return x / (1.0f + __expf(-2.0f*u));
}

__device__ inline void gload16(const void* g, void* l){
  __builtin_amdgcn_global_load_lds(
      (const __attribute__((address_space(1))) void*)g,
      (__attribute__((address_space(3))) void*)l, 16, 0, 0);
}

// LDS bank swizzle (both sides, involution): chunk c (16B) of row r stored at
// position c ^ ((r>>1)&3) within the row's 64B; stage sources the inverse-
// permuted global chunk so gload_lds dests stay linear. Verified: conflicts=0 (r11).

// ---------- fused transpose [R][C] f32 -> [C][R] bf16 for w1 AND w2 (1-D grid) ----------
__global__ __launch_bounds__(256) void transpose_both_kernel(
    const float* __restrict__ w1, const float* __restrict__ w2,
    ushort* __restrict__ w1t, ushort* __restrict__ w2t)
{
  __shared__ float tile[32][33];
  int bid = blockIdx.x;                 // 0..32767
  int which = bid >> 14;                // 16384 blocks per weight
  int r = bid & 16383;
  const float* src; ushort* dst; int R, C;
  if (which==0){ src=w1; dst=w1t; R=DM; C=HD; }
  else         { src=w2; dst=w2t; R=HD; C=DM; }
  int nbx = C/32, nby = R/32;           // 2048 blocks per expert
  int e = r / (nbx*nby); int rem = r % (nbx*nby);
  int c0 = (rem % nbx)*32, r0 = (rem / nbx)*32;
  src += (size_t)e*R*C; dst += (size_t)e*R*C;
  int tx = threadIdx.x & 31, ty = threadIdx.x >> 5;
  #pragma unroll
  for (int rr = ty; rr < 32; rr += 8)
    tile[rr][tx] = src[(size_t)(r0+rr)*C + c0+tx];
  __syncthreads();
  #pragma unroll
  for (int rr = ty; rr < 32; rr += 8)
    dst[(size_t)(c0+rr)*R + r0+tx] = f2bf(tile[tx][rr]);
}

// ---------- split x[N][256] f32 -> xs3[N][768] bf16 (hi|mid|lo 256-blocks) ----------
__global__ __launch_bounds__(256) void split_x_kernel(
    const float* __restrict__ x, ushort* __restrict__ xs3)
{
  int g = blockIdx.x*256 + threadIdx.x;     // one thread = 4 consecutive floats
  int e0 = g*4;
  int row = e0 >> 8, col = e0 & 255;
  f32x4 v = *(const f32x4*)(x + (size_t)row*D_IN + col);
  ushort4 hi, mi, lo;
  #pragma unroll
  for (int i=0;i<4;++i){
    float f = v[i];
    ushort h = f2bf(f);       float fh = bf2f(h);
    ushort m = f2bf(f - fh);  float fm = bf2f(m);
    ushort l = f2bf(f - fh - fm);
    ((ushort*)&hi)[i]=h; ((ushort*)&mi)[i]=m; ((ushort*)&lo)[i]=l;
  }
  ushort* base = xs3 + (size_t)row*768 + col;
  *(ushort4*)(base)       = hi;
  *(ushort4*)(base + 256) = mi;
  *(ushort4*)(base + 512) = lo;
}

// ---------- transpose+split w_in[256][1024] f32 -> wt3[1024][768] bf16 ----------
__global__ __launch_bounds__(256) void transpose_split3_kernel(
    const float* __restrict__ src, ushort* __restrict__ dst)
{
  __shared__ float tile[32][33];
  int c0 = blockIdx.x*32, r0 = blockIdx.y*32;
  int tx = threadIdx.x & 31, ty = threadIdx.x >> 5;
  #pragma unroll
  for (int rr = ty; rr < 32; rr += 8)
    tile[rr][tx] = src[(size_t)(r0+rr)*DM + c0+tx];
  __syncthreads();
  #pragma unroll
  for (int rr = ty; rr < 32; rr += 8){
    float f = tile[tx][rr];   // src[r0+tx][c0+rr]
    ushort h = f2bf(f);       float fh = bf2f(h);
    ushort m = f2bf(f - fh);  float fm = bf2f(m);
    ushort l = f2bf(f - fh - fm);
    ushort* d = dst + (size_t)(c0+rr)*768 + r0 + tx;
    d[0]   = h;
    d[256] = m;
    d[512] = l;
  }
}

// ---------- w_gate[1024][8] -> wgt[8][1024] ----------
__global__ __launch_bounds__(256) void wgate_t_kernel(
    const float* __restrict__ w_gate, float* __restrict__ wgt)
{
  int e = blockIdx.x;
  for (int j = threadIdx.x; j < DM; j += 256)
    wgt[(size_t)e*DM + j] = w_gate[(size_t)j*NE + e];
}

// ---------- router GEMM: y = x @ w_in + b_in via bf16x3 (6 terms, K=6*256) ----------
// 3-deep dbuf pipeline + bank-swizzled LDS + setprio around MFMA.
__global__ __launch_bounds__(256) void gemm_router(
    const ushort* __restrict__ A,    // [NTOK][768]
    const ushort* __restrict__ BT,   // [DM][768]
    const float* __restrict__ b_in,
    float* __restrict__ y)           // [NTOK][DM]
{
  __shared__ ushort As[3][128*32];
  __shared__ ushort Bs[3][128*32];
  const int tid = threadIdx.x;
  const int w = tid>>6, l = tid&63;
  const int wm = w>>1, wn = w&1;
  const int bm0 = blockIdx.y*128, bn0 = blockIdx.x*128;
  const int lr = l&15, lk = l>>4;
  const int rsub = l>>2;
  const int csub = ((l&3) ^ ((l>>3)&3)) * 8;   // swizzled source chunk

  const ushort* ag[2]; const ushort* bg[2];
  int aslot[2];
  #pragma unroll
  for (int i=0;i<2;++i){
    int ra = bm0 + w*32 + i*16 + rsub;
    int rb = bn0 + w*32 + i*16 + rsub;
    ag[i] = A  + (size_t)ra*768 + csub;
    bg[i] = BT + (size_t)rb*768 + csub;
    aslot[i] = (w*32 + i*16)*32;
  }

  const int pOffT[6] = {0,256,0,256,512,0};
  const int qOffT[6] = {0,0,256,256,0,512};
  auto stage = [&](int db, int t){
    int pOff = pOffT[t>>3] + (t&7)*32;
    int qOff = qOffT[t>>3] + (t&7)*32;
    #pragma unroll
    for (int i=0;i<2;++i){
      gload16(ag[i]+pOff, (ushort*)As[db] + aslot[i]);
      gload16(bg[i]+qOff, (ushort*)Bs[db] + aslot[i]);
    }
  };

  f32x4 acc[4][4] = {};
  const int NK = 48;
  stage(0, 0); stage(1, 1);
  int cur = 0;
  for (int t=0; t<NK; ++t){
    int sb = cur - 1; if (sb < 0) sb = 2;          // == (t+2)%3
    if (t+2 < NK)     { stage(sb, t+2); asm volatile("s_waitcnt vmcnt(8)" ::: "memory"); }
    else if (t+1 < NK){                 asm volatile("s_waitcnt vmcnt(4)" ::: "memory"); }
    else              {                 asm volatile("s_waitcnt vmcnt(0)" ::: "memory"); }
    __builtin_amdgcn_s_barrier();
    short8 af[4], bf[4];
    #pragma unroll
    for (int i=0;i<4;++i)
      af[i] = *(const short8*)(As[cur] + (wm*64 + i*16 + lr)*32 + (lk ^ ((lr>>1)&3))*8);
    #pragma unroll
    for (int j=0;j<4;++j)
      bf[j] = *(const short8*)(Bs[cur] + (wn*64 + j*16 + lr)*32 + (lk ^ ((lr>>1)&3))*8);
    __builtin_amdgcn_s_setprio(1);
    #pragma unroll
    for (int i=0;i<4;++i){
      #pragma unroll
      for (int j=0;j<4;++j)
        acc[i][j] = __builtin_amdgcn_mfma_f32_16x16x32_bf16(af[i], bf[j], acc[i][j], 0, 0, 0);
    }
    __builtin_amdgcn_s_setprio(0);
    __builtin_amdgcn_s_barrier();
    cur = cur + 1; if (cur > 2) cur = 0;
  }

  #pragma unroll
  for (int i=0;i<4;++i){
    #pragma unroll
    for (int j=0;j<4;++j){
      int n = bn0 + wn*64 + j*16 + lr;
      float bn_ = b_in[n];
      #pragma unroll
      for (int r=0;r<4;++r){
        int m = bm0 + wm*64 + i*16 + lk*4 + r;
        y[(size_t)m*DM + n] = acc[i][j][r] + bn_;
      }
    }
  }
}

// ---------- LN + logits + softmax top2 (wave per token), in-place on y ----------
__device__ inline double wredd(double v){
  #pragma unroll
  for (int o=32;o>0;o>>=1) v += __shfl_xor(v, o, 64);
  return v;
}

__global__ __launch_bounds__(256) void ln_router_kernel(
    const float* __restrict__ g_in, const float* __restrict__ beta_in,
    const float* __restrict__ wgt,
    ushort* __restrict__ hbf, float* __restrict__ resid,
    float* __restrict__ gates, int* __restrict__ selmask)
{
  int tok = blockIdx.x*4 + (threadIdx.x>>6);
  int l = threadIdx.x & 63;
  float* row = resid + (size_t)tok*DM;
  float u[16];
  double s=0.0, q=0.0;
  #pragma unroll
  for (int r=0;r<16;++r){ u[r]=row[l+64*r]; s+=u[r]; q+=(double)u[r]*u[r]; }
  s = wredd(s); q = wredd(q);
  double mean = s*(1.0/1024.0);
  double var  = q*(1.0/1024.0) - mean*mean;
  double rstd = 1.0/sqrt(var + 1e-5);

  double lg[NE];
  #pragma unroll
  for (int e=0;e<NE;++e) lg[e]=0.0;
  float hv[16];
  #pragma unroll
  for (int r=0;r<16;++r){
    int j = l + 64*r;
    double v = ((double)u[r]-mean)*rstd*(double)g_in[j] + (double)beta_in[j];
    hv[r] = (float)v;
    #pragma unroll
    for (int e=0;e<NE;++e) lg[e] += v*(double)wgt[(size_t)e*DM + j];
  }
  #pragma unroll
  for (int r=0;r<16;++r){
    int j = l + 64*r;
    row[j] = hv[r];
    hbf[(size_t)tok*DM + j] = f2bf(hv[r]);
  }
  #pragma unroll
  for (int e=0;e<NE;++e) lg[e] = wredd(lg[e]);

  if (l==0){
    double mx = lg[0];
    #pragma unroll
    for (int e=1;e<NE;++e) mx = lg[e]>mx ? lg[e] : mx;
    double p[NE]; double sum=0.0;
    #pragma unroll
    for (int e=0;e<NE;++e){ p[e]=exp(lg[e]-mx); sum+=p[e]; }
    #pragma unroll
    for (int e=0;e<NE;++e) p[e]/=sum;
    int i1=0;
    for (int e=1;e<NE;++e) if (p[e]>p[i1]) i1=e;
    int i2=-1;
    for (int e=0;e<NE;++e){ if (e==i1) continue; if (i2<0 || p[e]>p[i2]) i2=e; }
    double denom = p[i1]+p[i2]+1e-9;
    float g[NE];
    #pragma unroll
    for (int e=0;e<NE;++e) g[e]=0.f;
    g[i1]=(float)(p[i1]/denom);
    g[i2]=(float)(p[i2]/denom);
    #pragma unroll
    for (int e=0;e<NE;++e) gates[(size_t)tok*NE+e]=g[e];
    selmask[tok] = (1<<i1)|(1<<i2);
  }
}

// ---------- builders ----------
__global__ __launch_bounds__(256) void builder_count(
    const int* __restrict__ selmask, uint* __restrict__ bc1, uint* __restrict__ bc2)
{
  __shared__ uint c1[8], c2s[16];
  int b = blockIdx.x, tid = threadIdx.x;
  if (tid<8) c1[tid]=0;
  if (tid<16) c2s[tid]=0;
  __syncthreads();
  int m = selmask[b*256+tid];
  int ea = __ffs(m)-1, eb = 31-__clz(m);
  atomicAdd(&c1[ea],1u); atomicAdd(&c1[eb],1u);
  atomicAdd(&c2s[ea],1u); atomicAdd(&c2s[8+eb],1u);
  __syncthreads();
  if (tid<8) bc1[b*8+tid]=c1[tid];
  if (tid<16) bc2[b*16+tid]=c2s[tid];
}

__global__ __launch_bounds__(256) void builder_scan(
    const uint* __restrict__ bc1, const uint* __restrict__ bc2,
    uint* __restrict__ meta, int nch, int TPC)
{
  int tid = threadIdx.x;
  int c = tid/24, k = tid%24;
  if (c < nch){
    if (k < 8){
      uint run=0;
      for (int b=c*TPC; b<(c+1)*TPC; ++b){ meta[MT_TOFF1 + b*8 + k] = run; run += bc1[b*8+k]; }
      meta[MT_CNT1 + c*8 + k] = run;
    } else {
      int k2 = k-8;
      uint run=0;
      for (int b=c*TPC; b<(c+1)*TPC; ++b){ meta[MT_TOFF2 + b*16 + k2] = run; run += bc2[b*16+k2]; }
      meta[MT_CNT2 + c*16 + k2] = run;
      meta[MT_PCNT2 + c*16 + k2] = ((run + 127u)/128u)*128u;
    }
  }
  __syncthreads();
  if (tid < nch){
    uint off=0;
    for (int e=0;e<8;++e){
      uint cn = meta[MT_CNT1 + tid*8 + e];
      uint p = ((cn+127u)/128u)*128u;
      meta[MT_P1 + tid*8 + e] = p;
      meta[MT_OFF1 + tid*8 + e] = off;
      off += p;
    }
  }
}

__device__ inline int exclscan256(int v, int* sc, int tid){
  sc[tid]=v; __syncthreads();
  #pragma unroll
  for (int o=1;o<256;o<<=1){
    int x = (tid>=o) ? sc[tid-o] : 0;
    __syncthreads();
    sc[tid]+=x;
    __syncthreads();
  }
  int incl = sc[tid]; __syncthreads();
  return incl - v;
}

// L1 list per (chunk, expert): slot0 tokens first [0,cnt2a), then slot1 [cnt2a,cnt1)
__global__ __launch_bounds__(256) void builder_fill(
    const int* __restrict__ selmask, const uint* __restrict__ meta,
    int* __restrict__ ids1, int CH)
{
  __shared__ int sc[256];
  int b = blockIdx.x, tid = threadIdx.x;
  int t = b*256 + tid;
  int c = t / CH;
  int m = selmask[t];
  int ea = __ffs(m)-1, eb = 31-__clz(m);
  int ja=0, jb=0;
  for (int e=0;e<8;++e){
    int r0 = exclscan256((ea==e)?1:0, sc, tid);
    if (ea==e) ja = r0;
    int r1 = exclscan256((eb==e)?1:0, sc, tid);
    if (eb==e) jb = r1;
  }
  {
    uint j    = meta[MT_TOFF2 + b*16 + ea] + (uint)ja;       // slot0 position
    ids1[(c*8+ea)*CH + j] = t;
  }
  {
    uint j    = meta[MT_TOFF2 + b*16 + 8 + eb] + (uint)jb;   // slot1 position
    uint pos1 = meta[MT_CNT2 + c*16 + eb] + j;
    ids1[(c*8+eb)*CH + pos1] = t;
  }
}

// ---------- FFN-1: sparse gather-GEMM, m97 128^2 + 3-deep dbuf + swizzle (r11 proven) ----------
__global__ __launch_bounds__(256) void gemm_ffn1(
    const ushort* __restrict__ Abase,   // hbf
    const ushort* __restrict__ BT,      // w1t [E][HD][DM]
    const int*   __restrict__ rows,     // ids1 + c*8*CH
    const uint*  __restrict__ pcnt,     // P1
    const uint*  __restrict__ off1,
    const float* __restrict__ bias,     // b1
    ushort* __restrict__ t1,
    int K, int N, int CH)
{
  const int e = blockIdx.z;
  const int bm0 = blockIdx.y*128;
  if ((uint)bm0 >= pcnt[e]) return;
  const int bn0 = blockIdx.x*128;

  __shared__ ushort As[3][128*32];
  __shared__ ushort Bs[3][128*32];
  const int tid = threadIdx.x;
  const int w = tid>>6, l = tid&63;
  const int wm = w>>1, wn = w&1;
  const int lr = l&15, lk = l>>4;
  const int rsub = l>>2;
  const int csub = ((l&3) ^ ((l>>3)&3)) * 8;   // swizzled source chunk

  const ushort* ag[2]; const ushort* bg[2];
  int slot[2];
  #pragma unroll
  for (int i=0;i<2;++i){
    int ra = w*32 + i*16 + rsub;
    int id = rows[e*CH + bm0 + ra];
    ag[i] = Abase + (size_t)id*K + csub;
    int rb = bn0 + w*32 + i*16 + rsub;
    bg[i] = BT + (size_t)e*N*K + (size_t)rb*K + csub;
    slot[i] = (w*32 + i*16)*32;
  }

  auto stage = [&](int db, int kt){
    #pragma unroll
    for (int i=0;i<2;++i){
      gload16(ag[i]+kt, (ushort*)As[db] + slot[i]);
      gload16(bg[i]+kt, (ushort*)Bs[db] + slot[i]);
    }
  };

  f32x4 acc[4][4] = {};
  const int NK = K>>5;
  stage(0, 0); stage(1, 32);
  int cur = 0;
  for (int t=0; t<NK; ++t){
    int sb = cur - 1; if (sb < 0) sb = 2;          // == (t+2)%3
    if (t+2 < NK)     { stage(sb, (t+2)<<5); asm volatile("s_waitcnt vmcnt(8)" ::: "memory"); }
    else if (t+1 < NK){                      asm volatile("s_waitcnt vmcnt(4)" ::: "memory"); }
    else              {                      asm volatile("s_waitcnt vmcnt(0)" ::: "memory"); }
    __builtin_amdgcn_s_barrier();
    short8 af[4], bf[4];
    #pragma unroll
    for (int i=0;i<4;++i)
      af[i] = *(const short8*)(As[cur] + (wm*64 + i*16 + lr)*32 + (lk ^ ((lr>>1)&3))*8);
    #pragma unroll
    for (int j=0;j<4;++j)
      bf[j] = *(const short8*)(Bs[cur] + (wn*64 + j*16 + lr)*32 + (lk ^ ((lr>>1)&3))*8);
    __builtin_amdgcn_s_setprio(1);
    #pragma unroll
    for (int i=0;i<4;++i){
      #pragma unroll
      for (int j=0;j<4;++j)
        acc[i][j] = __builtin_amdgcn_mfma_f32_16x16x32_bf16(af[i], bf[j], acc[i][j], 0, 0, 0);
    }
    __builtin_amdgcn_s_setprio(0);
    __builtin_amdgcn_s_barrier();
    cur = cur + 1; if (cur > 2) cur = 0;
  }

  #pragma unroll
  for (int i=0;i<4;++i){
    #pragma unroll
    for (int j=0;j<4;++j){
      int n = bn0 + wn*64 + j*16 + lr;
      float bn_ = bias[(size_t)e*N + n];
      #pragma unroll
      for (int r=0;r<4;++r){
        int mloc = wm*64 + i*16 + lk*4 + r;
        float v = acc[i][j][r] + bn_;
        size_t trow = (size_t)off1[e] + bm0 + mloc;
        t1[trow*N + n] = f2bf(gelu_fast(v));
      }
    }
  }
}

// ---------- FFN-2: merged slots, DENSE-A GEMM + 3-deep dbuf + swizzle ----------
// z = blockIdx.z: e = z&7, slot = z>>3. Scatter via atomicAdd (each (tok,n) gets
// exactly 2 contributions, order-independent up to 1ulp f32 rounding).
__global__ __launch_bounds__(256) void gemm_ffn2(
    const ushort* __restrict__ t1,
    const ushort* __restrict__ BT,      // w2t [E][DM][HD]
    const int*   __restrict__ ids1,     // + c*8*CH
    const uint*  __restrict__ cnt2,     // [16] slot0 e0..7 | slot1 e0..7
    const uint*  __restrict__ pcnt2,    // [16] 128-padded
    const uint*  __restrict__ off1,
    const float* __restrict__ bias,     // b2
    const float* __restrict__ gates,
    float* __restrict__ resid,
    int K, int N, int CH)
{
  const int z = blockIdx.z;
  const int e = z & 7, sl = z >> 3;
  const int bm0 = blockIdx.y*128;
  if ((uint)bm0 >= pcnt2[sl*8 + e]) return;
  const uint scnt  = cnt2[sl*8 + e];
  const uint start = sl ? cnt2[e] : 0u;
  const int bn0 = blockIdx.x*128;

  __shared__ ushort As[3][128*32];
  __shared__ ushort Bs[3][128*32];
  const int tid = threadIdx.x;
  const int w = tid>>6, l = tid&63;
  const int wm = w>>1, wn = w&1;
  const int lr = l&15, lk = l>>4;
  const int rsub = l>>2;
  const int csub = ((l&3) ^ ((l>>3)&3)) * 8;   // swizzled source chunk

  const ushort* ag[2]; const ushort* bg[2];
  int slot[2];
  #pragma unroll
  for (int i=0;i<2;++i){
    int ra = w*32 + i*16 + rsub;
    size_t arow = (size_t)off1[e] + start + bm0 + ra;   // dense, no gather
    ag[i] = t1 + arow*K + csub;
    int rb = bn0 + w*32 + i*16 + rsub;
    bg[i] = BT + (size_t)e*N*K + (size_t)rb*K + csub;
    slot[i] = (w*32 + i*16)*32;
  }

  auto stage = [&](int db, int kt){
    #pragma unroll
    for (int i=0;i<2;++i){
      gload16(ag[i]+kt, (ushort*)As[db] + slot[i]);
      gload16(bg[i]+kt, (ushort*)Bs[db] + slot[i]);
    }
  };

  f32x4 acc[4][4] = {};
  const int NK = K>>5;
  stage(0, 0); stage(1, 32);
  int cur = 0;
  for (int t=0; t<NK; ++t){
    int sb = cur - 1; if (sb < 0) sb = 2;          // == (t+2)%3
    if (t+2 < NK)     { stage(sb, (t+2)<<5); asm volatile("s_waitcnt vmcnt(8)" ::: "memory"); }
    else if (t+1 < NK){                      asm volatile("s_waitcnt vmcnt(4)" ::: "memory"); }
    else              {                      asm volatile("s_waitcnt vmcnt(0)" ::: "memory"); }
    __builtin_amdgcn_s_barrier();
    short8 af[4], bf[4];
    #pragma unroll
    for (int i=0;i<4;++i)
      af[i] = *(const short8*)(As[cur] + (wm*64 + i*16 + lr)*32 + (lk ^ ((lr>>1)&3))*8);
    #pragma unroll
    for (int j=0;j<4;++j)
      bf[j] = *(const short8*)(Bs[cur] + (wn*64 + j*16 + lr)*32 + (lk ^ ((lr>>1)&3))*8);
    __builtin_amdgcn_s_setprio(1);
    #pragma unroll
    for (int i=0;i<4;++i){
      #pragma unroll
      for (int j=0;j<4;++j)
        acc[i][j] = __builtin_amdgcn_mfma_f32_16x16x32_bf16(af[i], bf[j], acc[i][j], 0, 0, 0);
    }
    __builtin_amdgcn_s_setprio(0);
    __builtin_amdgcn_s_barrier();
    cur = cur + 1; if (cur > 2) cur = 0;
  }

  #pragma unroll
  for (int i=0;i<4;++i){
    #pragma unroll
    for (int j=0;j<4;++j){
      int n = bn0 + wn*64 + j*16 + lr;
      float bn_ = bias[(size_t)e*N + n];
      #pragma unroll
      for (int r=0;r<4;++r){
        int mloc = wm*64 + i*16 + lk*4 + r;
        int mg = bm0 + mloc;
        if ((uint)mg < scnt){
          int tok = ids1[e*CH + (int)start + mg];
          float g = gates[(size_t)tok*NE + e];
          atomicAdd(&resid[(size_t)tok*N + n], g*(acc[i][j][r] + bn_));
        }
      }
    }
  }
}

// ---------- final: LN(resid) -> LN -> @w_cls + b_cls (4 tokens/block) ----------
__global__ __launch_bounds__(256) void final_kernel(
    const float* __restrict__ resid,
    const float* __restrict__ g_moe, const float* __restrict__ beta_moe,
    const float* __restrict__ g_out, const float* __restrict__ beta_out,
    const float* __restrict__ w_cls, const float* __restrict__ b_cls,
    float* __restrict__ out)
{
  int tok = blockIdx.x*4 + (threadIdx.x>>6);
  int l = threadIdx.x & 63;
  const float* row = resid + (size_t)tok*DM;
  float u[16];
  double s=0.0,q=0.0;
  #pragma unroll
  for (int r=0;r<16;++r){ u[r]=row[l + 64*r]; s+=u[r]; q+=(double)u[r]*u[r]; }
  s=wredd(s); q=wredd(q);
  double m1 = s*(1.0/1024.0), v1 = q*(1.0/1024.0)-m1*m1;
  double rs1 = 1.0/sqrt(v1+1e-5);
  float tv[16]; double s2=0.0,q2=0.0;
  #pragma unroll
  for (int r=0;r<16;++r){
    int j = l+64*r;
    float vv = (float)((u[r]-m1)*rs1)*g_moe[j] + beta_moe[j];
    tv[r]=vv; s2+=vv; q2+=(double)vv*vv;
  }
  s2=wredd(s2); q2=wredd(q2);
  double m2=s2*(1.0/1024.0), v2=q2*(1.0/1024.0)-m2*m2;
  double rs2=1.0/sqrt(v2+1e-5);
  double p0=0.0,p1=0.0;
  #pragma unroll
  for (int r=0;r<16;++r){
    int j=l+64*r;
    double y=((double)tv[r]-m2)*rs2*(double)g_out[j]+(double)beta_out[j];
    p0+=y*(double)w_cls[j*2]; p1+=y*(double)w_cls[j*2+1];
  }
  p0=wredd(p0); p1=wredd(p1);
  if (l==0){
    out[(size_t)tok*2  ]=(float)(p0+(double)b_cls[0]);
    out[(size_t)tok*2+1]=(float)(p1+(double)b_cls[1]);
  }
}

extern "C" void kernel_launch(void* const* d_in, const int* in_sizes, int n_in,
                              void* d_out, int out_size, void* d_ws, size_t ws_size,
                              hipStream_t stream)
{
  (void)in_sizes; (void)n_in; (void)out_size;
  const float* x       = (const float*)d_in[0];
  const float* w_in    = (const float*)d_in[1];
  const float* b_in    = (const float*)d_in[2];
  const float* g_in    = (const float*)d_in[3];
  const float* beta_in = (const float*)d_in[4];
  const float* w_gate  = (const float*)d_in[5];
  const float* w1      = (const float*)d_in[6];
  const float* b1      = (const float*)d_in[7];
  const float* w2      = (const float*)d_in[8];
  const float* b2      = (const float*)d_in[9];
  const float* g_moe   = (const float*)d_in[10];
  const float* beta_mo = (const float*)d_in[11];
  const float* g_out   = (const float*)d_in[12];
  const float* beta_ou = (const float*)d_in[13];
  const float* w_cls   = (const float*)d_in[14];
  const float* b_cls   = (const float*)d_in[15];
  float* out = (float*)d_out;

  // ---- workspace carve ----
  char* p = (char*)d_ws;
  ushort* w1t   = (ushort*)p; p += (size_t)NE*HD*DM*2;
  ushort* w2t   = (ushort*)p; p += (size_t)NE*DM*HD*2;
  ushort* hbf   = (ushort*)p; p += (size_t)NTOK*DM*2;
  float*  resid = (float*)p;  p += (size_t)NTOK*DM*4;      // also router-GEMM y
  float*  gates = (float*)p;  p += (size_t)NTOK*NE*4;
  int*    selmk = (int*)p;    p += (size_t)NTOK*4;
  int*    ids1  = (int*)p;    p += (size_t)NE*NTOK*4;
  ushort* wt3   = (ushort*)p; p += (size_t)DM*768*2;
  float*  wgt   = (float*)p;  p += (size_t)NE*DM*4;
  uint*   bc1   = (uint*)p;   p += (size_t)64*8*4;
  uint*   bc2   = (uint*)p;   p += (size_t)64*16*4;
  uint*   meta  = (uint*)p;   p += (size_t)MT_TOTAL*4;
  size_t fixed = (size_t)(p - (char*)d_ws);

  const size_t xs3_bytes = (size_t)NTOK*768*2;             // 25.2 MB
  size_t t1b1 = ((size_t)2*NTOK        + 2048)*HD*2;       // 138.5 MB
  size_t t1b2 = ((size_t)2*(NTOK/2)    + 2048)*HD*2;
  size_t t1b4 = ((size_t)2*(NTOK/4)    + 2048)*HD*2;
  int nch = 8;
  if      (ws_size >= fixed + (t1b1 > xs3_bytes ? t1b1 : xs3_bytes)) nch = 1;
  else if (ws_size >= fixed + (t1b2 > xs3_bytes ? t1b2 : xs3_bytes)) nch = 2;
  else if (ws_size >= fixed + (t1b4 > xs3_bytes ? t1b4 : xs3_bytes)) nch = 4;
  const int CH  = NTOK/nch;
  const int TPC = CH/256;
  ushort* t1  = (ushort*)p;
  ushort* xs3 = (ushort*)p;       // aliases t1 (dead before t1 written)

  // ---- router path (bf16x3 MFMA emulated-f32) ----
  split_x_kernel<<<dim3(NTOK*D_IN/4/256), 256, 0, stream>>>(x, xs3);
  transpose_split3_kernel<<<dim3(DM/32, D_IN/32), 256, 0, stream>>>(w_in, wt3);
  wgate_t_kernel<<<dim3(NE), 256, 0, stream>>>(w_gate, wgt);
  transpose_both_kernel<<<dim3(32768), 256, 0, stream>>>(w1, w2, w1t, w2t);

  gemm_router<<<dim3(DM/128, NTOK/128), 256, 0, stream>>>(xs3, wt3, b_in, resid);
  ln_router_kernel<<<dim3(NTOK/4), 256, 0, stream>>>(g_in, beta_in, wgt,
                                                     hbf, resid, gates, selmk);

  hipMemsetAsync(ids1, 0, (size_t)NE*NTOK*4, stream);

  builder_count<<<dim3(NTOK/256), 256, 0, stream>>>(selmk, bc1, bc2);
  builder_scan<<<dim3(1), 256, 0, stream>>>(bc1, bc2, meta, nch, TPC);
  builder_fill<<<dim3(NTOK/256), 256, 0, stream>>>(selmk, meta, ids1, CH);

  for (int c = 0; c < nch; ++c) {
    gemm_ffn1<<<dim3(HD/128, CH/128, NE), 256, 0, stream>>>(
        hbf, w1t, ids1 + (size_t)c*8*CH,
        meta+MT_P1+c*8, meta+MT_OFF1+c*8, b1, t1, DM, HD, CH);
    gemm_ffn2<<<dim3(DM/128, CH/128, 2*NE), 256, 0, stream>>>(
        t1, w2t, ids1 + (size_t)c*8*CH,
        meta+MT_CNT2+c*16, meta+MT_PCNT2+c*16, meta+MT_OFF1+c*8,
        b2, gates, resid, HD, DM, CH);
  }

  final_kernel<<<dim3(NTOK/4), 256, 0, stream>>>(resid, g_moe, beta_mo, g_out, beta_ou,
                                                 w_cls, b_cls, out);
}

// Round 14
// 891.059 us; speedup vs baseline: 1.0145x; 1.0019x over previous
//
#include <hip/hip_runtime.h>
#include <hip/hip_bf16.h>

#define D_IN 256
#define DM   1024
#define HD   2048
#define NE   8
#define NTOK 16384

typedef __attribute__((ext_vector_type(8))) short short8;
typedef __attribute__((ext_vector_type(4))) float f32x4;
typedef unsigned int uint;

// ---- meta layout (uint indices) ----
#define MT_TOFF1 0      // [64][8]
#define MT_TOFF2 512    // [64][16]
#define MT_CNT1  1536   // [8][8]
#define MT_P1    1600   // [8][8]    roundup128(cnt1)
#define MT_OFF1  1664   // [8][8]
#define MT_CNT2  1728   // [8][16]   [slot0 e0..7 | slot1 e0..7]
#define MT_PCNT2 1856   // [8][16]   roundup128(cnt2)
#define MT_TOTAL 1984

__device__ inline ushort f2bf(float v){
  __hip_bfloat16 b = __float2bfloat16(v);
  return *reinterpret_cast<ushort*>(&b);
}
__device__ inline float bf2f(ushort u){
  __hip_bfloat16 b = *reinterpret_cast<__hip_bfloat16*>(&u);
  return __bfloat162float(b);
}

// gelu tanh-approx via identity 0.5*(1+tanh(u)) = sigmoid(2u)
__device__ inline float gelu_fast(float x){
  float u = 0.7978845608028654f * x * (1.0f + 0.044715f*x*x);
  return x / (1.0f + __expf(-2.0f*u));
}

__device__ inline void gload16(const void* g, void* l){
  __builtin_amdgcn_global_load_lds(
      (const __attribute__((address_space(1))) void*)g,
      (__attribute__((address_space(3))) void*)l, 16, 0, 0);
}

// LDS bank swizzle (both sides, involution): chunk c (16B) of row r stored at
// position c ^ ((r>>1)&3) within the row's 64B; stage sources the inverse-
// permuted global chunk so gload_lds dests stay linear. Verified: conflicts=0 (r11).

// ---------- fused transpose [R][C] f32 -> [C][R] bf16 for w1 AND w2 (1-D grid) ----------
__global__ __launch_bounds__(256) void transpose_both_kernel(
    const float* __restrict__ w1, const float* __restrict__ w2,
    ushort* __restrict__ w1t, ushort* __restrict__ w2t)
{
  __shared__ float tile[32][33];
  int bid = blockIdx.x;                 // 0..32767
  int which = bid >> 14;                // 16384 blocks per weight
  int r = bid & 16383;
  const float* src; ushort* dst; int R, C;
  if (which==0){ src=w1; dst=w1t; R=DM; C=HD; }
  else         { src=w2; dst=w2t; R=HD; C=DM; }
  int nbx = C/32, nby = R/32;           // 2048 blocks per expert
  int e = r / (nbx*nby); int rem = r % (nbx*nby);
  int c0 = (rem % nbx)*32, r0 = (rem / nbx)*32;
  src += (size_t)e*R*C; dst += (size_t)e*R*C;
  int tx = threadIdx.x & 31, ty = threadIdx.x >> 5;
  #pragma unroll
  for (int rr = ty; rr < 32; rr += 8)
    tile[rr][tx] = src[(size_t)(r0+rr)*C + c0+tx];
  __syncthreads();
  #pragma unroll
  for (int rr = ty; rr < 32; rr += 8)
    dst[(size_t)(c0+rr)*R + r0+tx] = f2bf(tile[tx][rr]);
}

// ---------- split x[N][256] f32 -> xs3[N][768] bf16 (hi|mid|lo 256-blocks) ----------
__global__ __launch_bounds__(256) void split_x_kernel(
    const float* __restrict__ x, ushort* __restrict__ xs3)
{
  int g = blockIdx.x*256 + threadIdx.x;     // one thread = 4 consecutive floats
  int e0 = g*4;
  int row = e0 >> 8, col = e0 & 255;
  f32x4 v = *(const f32x4*)(x + (size_t)row*D_IN + col);
  ushort4 hi, mi, lo;
  #pragma unroll
  for (int i=0;i<4;++i){
    float f = v[i];
    ushort h = f2bf(f);       float fh = bf2f(h);
    ushort m = f2bf(f - fh);  float fm = bf2f(m);
    ushort l = f2bf(f - fh - fm);
    ((ushort*)&hi)[i]=h; ((ushort*)&mi)[i]=m; ((ushort*)&lo)[i]=l;
  }
  ushort* base = xs3 + (size_t)row*768 + col;
  *(ushort4*)(base)       = hi;
  *(ushort4*)(base + 256) = mi;
  *(ushort4*)(base + 512) = lo;
}

// ---------- transpose+split w_in[256][1024] f32 -> wt3[1024][768] bf16 ----------
__global__ __launch_bounds__(256) void transpose_split3_kernel(
    const float* __restrict__ src, ushort* __restrict__ dst)
{
  __shared__ float tile[32][33];
  int c0 = blockIdx.x*32, r0 = blockIdx.y*32;
  int tx = threadIdx.x & 31, ty = threadIdx.x >> 5;
  #pragma unroll
  for (int rr = ty; rr < 32; rr += 8)
    tile[rr][tx] = src[(size_t)(r0+rr)*DM + c0+tx];
  __syncthreads();
  #pragma unroll
  for (int rr = ty; rr < 32; rr += 8){
    float f = tile[tx][rr];   // src[r0+tx][c0+rr]
    ushort h = f2bf(f);       float fh = bf2f(h);
    ushort m = f2bf(f - fh);  float fm = bf2f(m);
    ushort l = f2bf(f - fh - fm);
    ushort* d = dst + (size_t)(c0+rr)*768 + r0 + tx;
    d[0]   = h;
    d[256] = m;
    d[512] = l;
  }
}

// ---------- w_gate[1024][8] -> wgt[8][1024] ----------
__global__ __launch_bounds__(256) void wgate_t_kernel(
    const float* __restrict__ w_gate, float* __restrict__ wgt)
{
  int e = blockIdx.x;
  for (int j = threadIdx.x; j < DM; j += 256)
    wgt[(size_t)e*DM + j] = w_gate[(size_t)j*NE + e];
}

// ---------- router GEMM: y = x @ w_in + b_in via bf16x3 (6 terms, K=6*256) ----------
// 3-deep dbuf pipeline + bank-swizzled LDS + setprio around MFMA.
__global__ __launch_bounds__(256) void gemm_router(
    const ushort* __restrict__ A,    // [NTOK][768]
    const ushort* __restrict__ BT,   // [DM][768]
    const float* __restrict__ b_in,
    float* __restrict__ y)           // [NTOK][DM]
{
  __shared__ ushort As[3][128*32];
  __shared__ ushort Bs[3][128*32];
  const int tid = threadIdx.x;
  const int w = tid>>6, l = tid&63;
  const int wm = w>>1, wn = w&1;
  const int bm0 = blockIdx.y*128, bn0 = blockIdx.x*128;
  const int lr = l&15, lk = l>>4;
  const int rsub = l>>2;
  const int csub = ((l&3) ^ ((l>>3)&3)) * 8;   // swizzled source chunk

  const ushort* ag[2]; const ushort* bg[2];
  int aslot[2];
  #pragma unroll
  for (int i=0;i<2;++i){
    int ra = bm0 + w*32 + i*16 + rsub;
    int rb = bn0 + w*32 + i*16 + rsub;
    ag[i] = A  + (size_t)ra*768 + csub;
    bg[i] = BT + (size_t)rb*768 + csub;
    aslot[i] = (w*32 + i*16)*32;
  }

  const int pOffT[6] = {0,256,0,256,512,0};
  const int qOffT[6] = {0,0,256,256,0,512};
  auto stage = [&](int db, int t){
    int pOff = pOffT[t>>3] + (t&7)*32;
    int qOff = qOffT[t>>3] + (t&7)*32;
    #pragma unroll
    for (int i=0;i<2;++i){
      gload16(ag[i]+pOff, (ushort*)As[db] + aslot[i]);
      gload16(bg[i]+qOff, (ushort*)Bs[db] + aslot[i]);
    }
  };

  f32x4 acc[4][4] = {};
  const int NK = 48;
  stage(0, 0); stage(1, 1);
  int cur = 0;
  for (int t=0; t<NK; ++t){
    int sb = cur - 1; if (sb < 0) sb = 2;          // == (t+2)%3
    if (t+2 < NK)     { stage(sb, t+2); asm volatile("s_waitcnt vmcnt(8)" ::: "memory"); }
    else if (t+1 < NK){                 asm volatile("s_waitcnt vmcnt(4)" ::: "memory"); }
    else              {                 asm volatile("s_waitcnt vmcnt(0)" ::: "memory"); }
    __builtin_amdgcn_s_barrier();
    short8 af[4], bf[4];
    #pragma unroll
    for (int i=0;i<4;++i)
      af[i] = *(const short8*)(As[cur] + (wm*64 + i*16 + lr)*32 + (lk ^ ((lr>>1)&3))*8);
    #pragma unroll
    for (int j=0;j<4;++j)
      bf[j] = *(const short8*)(Bs[cur] + (wn*64 + j*16 + lr)*32 + (lk ^ ((lr>>1)&3))*8);
    __builtin_amdgcn_s_setprio(1);
    #pragma unroll
    for (int i=0;i<4;++i){
      #pragma unroll
      for (int j=0;j<4;++j)
        acc[i][j] = __builtin_amdgcn_mfma_f32_16x16x32_bf16(af[i], bf[j], acc[i][j], 0, 0, 0);
    }
    __builtin_amdgcn_s_setprio(0);
    __builtin_amdgcn_s_barrier();
    cur = cur + 1; if (cur > 2) cur = 0;
  }

  #pragma unroll
  for (int i=0;i<4;++i){
    #pragma unroll
    for (int j=0;j<4;++j){
      int n = bn0 + wn*64 + j*16 + lr;
      float bn_ = b_in[n];
      #pragma unroll
      for (int r=0;r<4;++r){
        int m = bm0 + wm*64 + i*16 + lk*4 + r;
        y[(size_t)m*DM + n] = acc[i][j][r] + bn_;
      }
    }
  }
}

// ---------- LN + logits + softmax top2 (wave per token), in-place on y ----------
__device__ inline double wredd(double v){
  #pragma unroll
  for (int o=32;o>0;o>>=1) v += __shfl_xor(v, o, 64);
  return v;
}

__global__ __launch_bounds__(256) void ln_router_kernel(
    const float* __restrict__ g_in, const float* __restrict__ beta_in,
    const float* __restrict__ wgt,
    ushort* __restrict__ hbf, float* __restrict__ resid,
    float* __restrict__ gates, int* __restrict__ selmask)
{
  int tok = blockIdx.x*4 + (threadIdx.x>>6);
  int l = threadIdx.x & 63;
  float* row = resid + (size_t)tok*DM;
  float u[16];
  double s=0.0, q=0.0;
  #pragma unroll
  for (int r=0;r<16;++r){ u[r]=row[l+64*r]; s+=u[r]; q+=(double)u[r]*u[r]; }
  s = wredd(s); q = wredd(q);
  double mean = s*(1.0/1024.0);
  double var  = q*(1.0/1024.0) - mean*mean;
  double rstd = 1.0/sqrt(var + 1e-5);

  double lg[NE];
  #pragma unroll
  for (int e=0;e<NE;++e) lg[e]=0.0;
  float hv[16];
  #pragma unroll
  for (int r=0;r<16;++r){
    int j = l + 64*r;
    double v = ((double)u[r]-mean)*rstd*(double)g_in[j] + (double)beta_in[j];
    hv[r] = (float)v;
    #pragma unroll
    for (int e=0;e<NE;++e) lg[e] += v*(double)wgt[(size_t)e*DM + j];
  }
  #pragma unroll
  for (int r=0;r<16;++r){
    int j = l + 64*r;
    row[j] = hv[r];
    hbf[(size_t)tok*DM + j] = f2bf(hv[r]);
  }
  #pragma unroll
  for (int e=0;e<NE;++e) lg[e] = wredd(lg[e]);

  if (l==0){
    double mx = lg[0];
    #pragma unroll
    for (int e=1;e<NE;++e) mx = lg[e]>mx ? lg[e] : mx;
    double p[NE]; double sum=0.0;
    #pragma unroll
    for (int e=0;e<NE;++e){ p[e]=exp(lg[e]-mx); sum+=p[e]; }
    #pragma unroll
    for (int e=0;e<NE;++e) p[e]/=sum;
    int i1=0;
    for (int e=1;e<NE;++e) if (p[e]>p[i1]) i1=e;
    int i2=-1;
    for (int e=0;e<NE;++e){ if (e==i1) continue; if (i2<0 || p[e]>p[i2]) i2=e; }
    double denom = p[i1]+p[i2]+1e-9;
    float g[NE];
    #pragma unroll
    for (int e=0;e<NE;++e) g[e]=0.f;
    g[i1]=(float)(p[i1]/denom);
    g[i2]=(float)(p[i2]/denom);
    #pragma unroll
    for (int e=0;e<NE;++e) gates[(size_t)tok*NE+e]=g[e];
    selmask[tok] = (1<<i1)|(1<<i2);
  }
}

// ---------- builders ----------
__global__ __launch_bounds__(256) void builder_count(
    const int* __restrict__ selmask, uint* __restrict__ bc1, uint* __restrict__ bc2)
{
  __shared__ uint c1[8], c2s[16];
  int b = blockIdx.x, tid = threadIdx.x;
  if (tid<8) c1[tid]=0;
  if (tid<16) c2s[tid]=0;
  __syncthreads();
  int m = selmask[b*256+tid];
  int ea = __ffs(m)-1, eb = 31-__clz(m);
  atomicAdd(&c1[ea],1u); atomicAdd(&c1[eb],1u);
  atomicAdd(&c2s[ea],1u); atomicAdd(&c2s[8+eb],1u);
  __syncthreads();
  if (tid<8) bc1[b*8+tid]=c1[tid];
  if (tid<16) bc2[b*16+tid]=c2s[tid];
}

__global__ __launch_bounds__(256) void builder_scan(
    const uint* __restrict__ bc1, const uint* __restrict__ bc2,
    uint* __restrict__ meta, int nch, int TPC)
{
  int tid = threadIdx.x;
  int c = tid/24, k = tid%24;
  if (c < nch){
    if (k < 8){
      uint run=0;
      for (int b=c*TPC; b<(c+1)*TPC; ++b){ meta[MT_TOFF1 + b*8 + k] = run; run += bc1[b*8+k]; }
      meta[MT_CNT1 + c*8 + k] = run;
    } else {
      int k2 = k-8;
      uint run=0;
      for (int b=c*TPC; b<(c+1)*TPC; ++b){ meta[MT_TOFF2 + b*16 + k2] = run; run += bc2[b*16+k2]; }
      meta[MT_CNT2 + c*16 + k2] = run;
      meta[MT_PCNT2 + c*16 + k2] = ((run + 127u)/128u)*128u;
    }
  }
  __syncthreads();
  if (tid < nch){
    uint off=0;
    for (int e=0;e<8;++e){
      uint cn = meta[MT_CNT1 + tid*8 + e];
      uint p = ((cn+127u)/128u)*128u;
      meta[MT_P1 + tid*8 + e] = p;
      meta[MT_OFF1 + tid*8 + e] = off;
      off += p;
    }
  }
}

__device__ inline int exclscan256(int v, int* sc, int tid){
  sc[tid]=v; __syncthreads();
  #pragma unroll
  for (int o=1;o<256;o<<=1){
    int x = (tid>=o) ? sc[tid-o] : 0;
    __syncthreads();
    sc[tid]+=x;
    __syncthreads();
  }
  int incl = sc[tid]; __syncthreads();
  return incl - v;
}

// L1 list per (chunk, expert): slot0 tokens first [0,cnt2a), then slot1 [cnt2a,cnt1)
__global__ __launch_bounds__(256) void builder_fill(
    const int* __restrict__ selmask, const uint* __restrict__ meta,
    int* __restrict__ ids1, int CH)
{
  __shared__ int sc[256];
  int b = blockIdx.x, tid = threadIdx.x;
  int t = b*256 + tid;
  int c = t / CH;
  int m = selmask[t];
  int ea = __ffs(m)-1, eb = 31-__clz(m);
  int ja=0, jb=0;
  for (int e=0;e<8;++e){
    int r0 = exclscan256((ea==e)?1:0, sc, tid);
    if (ea==e) ja = r0;
    int r1 = exclscan256((eb==e)?1:0, sc, tid);
    if (eb==e) jb = r1;
  }
  {
    uint j    = meta[MT_TOFF2 + b*16 + ea] + (uint)ja;       // slot0 position
    ids1[(c*8+ea)*CH + j] = t;
  }
  {
    uint j    = meta[MT_TOFF2 + b*16 + 8 + eb] + (uint)jb;   // slot1 position
    uint pos1 = meta[MT_CNT2 + c*16 + eb] + j;
    ids1[(c*8+eb)*CH + pos1] = t;
  }
}

// ---------- FFN-1: sparse gather-GEMM, m97 128^2 + 3-deep dbuf + swizzle (r11 proven) ----------
__global__ __launch_bounds__(256) void gemm_ffn1(
    const ushort* __restrict__ Abase,   // hbf
    const ushort* __restrict__ BT,      // w1t [E][HD][DM]
    const int*   __restrict__ rows,     // ids1 + c*8*CH
    const uint*  __restrict__ pcnt,     // P1
    const uint*  __restrict__ off1,
    const float* __restrict__ bias,     // b1
    ushort* __restrict__ t1,
    int K, int N, int CH)
{
  const int e = blockIdx.z;
  const int bm0 = blockIdx.y*128;
  if ((uint)bm0 >= pcnt[e]) return;
  const int bn0 = blockIdx.x*128;

  __shared__ ushort As[3][128*32];
  __shared__ ushort Bs[3][128*32];
  const int tid = threadIdx.x;
  const int w = tid>>6, l = tid&63;
  const int wm = w>>1, wn = w&1;
  const int lr = l&15, lk = l>>4;
  const int rsub = l>>2;
  const int csub = ((l&3) ^ ((l>>3)&3)) * 8;   // swizzled source chunk

  const ushort* ag[2]; const ushort* bg[2];
  int slot[2];
  #pragma unroll
  for (int i=0;i<2;++i){
    int ra = w*32 + i*16 + rsub;
    int id = rows[e*CH + bm0 + ra];
    ag[i] = Abase + (size_t)id*K + csub;
    int rb = bn0 + w*32 + i*16 + rsub;
    bg[i] = BT + (size_t)e*N*K + (size_t)rb*K + csub;
    slot[i] = (w*32 + i*16)*32;
  }

  auto stage = [&](int db, int kt){
    #pragma unroll
    for (int i=0;i<2;++i){
      gload16(ag[i]+kt, (ushort*)As[db] + slot[i]);
      gload16(bg[i]+kt, (ushort*)Bs[db] + slot[i]);
    }
  };

  f32x4 acc[4][4] = {};
  const int NK = K>>5;
  stage(0, 0); stage(1, 32);
  int cur = 0;
  for (int t=0; t<NK; ++t){
    int sb = cur - 1; if (sb < 0) sb = 2;          // == (t+2)%3
    if (t+2 < NK)     { stage(sb, (t+2)<<5); asm volatile("s_waitcnt vmcnt(8)" ::: "memory"); }
    else if (t+1 < NK){                      asm volatile("s_waitcnt vmcnt(4)" ::: "memory"); }
    else              {                      asm volatile("s_waitcnt vmcnt(0)" ::: "memory"); }
    __builtin_amdgcn_s_barrier();
    short8 af[4], bf[4];
    #pragma unroll
    for (int i=0;i<4;++i)
      af[i] = *(const short8*)(As[cur] + (wm*64 + i*16 + lr)*32 + (lk ^ ((lr>>1)&3))*8);
    #pragma unroll
    for (int j=0;j<4;++j)
      bf[j] = *(const short8*)(Bs[cur] + (wn*64 + j*16 + lr)*32 + (lk ^ ((lr>>1)&3))*8);
    __builtin_amdgcn_s_setprio(1);
    #pragma unroll
    for (int i=0;i<4;++i){
      #pragma unroll
      for (int j=0;j<4;++j)
        acc[i][j] = __builtin_amdgcn_mfma_f32_16x16x32_bf16(af[i], bf[j], acc[i][j], 0, 0, 0);
    }
    __builtin_amdgcn_s_setprio(0);
    __builtin_amdgcn_s_barrier();
    cur = cur + 1; if (cur > 2) cur = 0;
  }

  #pragma unroll
  for (int i=0;i<4;++i){
    #pragma unroll
    for (int j=0;j<4;++j){
      int n = bn0 + wn*64 + j*16 + lr;
      float bn_ = bias[(size_t)e*N + n];
      #pragma unroll
      for (int r=0;r<4;++r){
        int mloc = wm*64 + i*16 + lk*4 + r;
        float v = acc[i][j][r] + bn_;
        size_t trow = (size_t)off1[e] + bm0 + mloc;
        t1[trow*N + n] = f2bf(gelu_fast(v));
      }
    }
  }
}

// ---------- FFN-2: FULL per-expert L1 list (no slot split), DENSE-A GEMM ----------
// Within one expert's list a token appears at most once (top1 != top2), so the
// only scatter race is ACROSS experts -> handled by atomicAdd (r13 proven,
// absmax unchanged). z = expert (8 slices vs 16 -> half the B-panel L2 thrash,
// half the padding waste).
__global__ __launch_bounds__(256) void gemm_ffn2(
    const ushort* __restrict__ t1,
    const ushort* __restrict__ BT,      // w2t [E][DM][HD]
    const int*   __restrict__ ids1,     // + c*8*CH
    const uint*  __restrict__ cnt1,     // [8]
    const uint*  __restrict__ pcnt1,    // [8] 128-padded
    const uint*  __restrict__ off1,
    const float* __restrict__ bias,     // b2
    const float* __restrict__ gates,
    float* __restrict__ resid,
    int K, int N, int CH)
{
  const int e = blockIdx.z;
  const int bm0 = blockIdx.y*128;
  if ((uint)bm0 >= pcnt1[e]) return;
  const uint scnt = cnt1[e];
  const int bn0 = blockIdx.x*128;

  __shared__ ushort As[3][128*32];
  __shared__ ushort Bs[3][128*32];
  const int tid = threadIdx.x;
  const int w = tid>>6, l = tid&63;
  const int wm = w>>1, wn = w&1;
  const int lr = l&15, lk = l>>4;
  const int rsub = l>>2;
  const int csub = ((l&3) ^ ((l>>3)&3)) * 8;   // swizzled source chunk

  const ushort* ag[2]; const ushort* bg[2];
  int slot[2];
  #pragma unroll
  for (int i=0;i<2;++i){
    int ra = w*32 + i*16 + rsub;
    size_t arow = (size_t)off1[e] + bm0 + ra;   // dense rows 0..cnt1
    ag[i] = t1 + arow*K + csub;
    int rb = bn0 + w*32 + i*16 + rsub;
    bg[i] = BT + (size_t)e*N*K + (size_t)rb*K + csub;
    slot[i] = (w*32 + i*16)*32;
  }

  auto stage = [&](int db, int kt){
    #pragma unroll
    for (int i=0;i<2;++i){
      gload16(ag[i]+kt, (ushort*)As[db] + slot[i]);
      gload16(bg[i]+kt, (ushort*)Bs[db] + slot[i]);
    }
  };

  f32x4 acc[4][4] = {};
  const int NK = K>>5;
  stage(0, 0); stage(1, 32);
  int cur = 0;
  for (int t=0; t<NK; ++t){
    int sb = cur - 1; if (sb < 0) sb = 2;          // == (t+2)%3
    if (t+2 < NK)     { stage(sb, (t+2)<<5); asm volatile("s_waitcnt vmcnt(8)" ::: "memory"); }
    else if (t+1 < NK){                      asm volatile("s_waitcnt vmcnt(4)" ::: "memory"); }
    else              {                      asm volatile("s_waitcnt vmcnt(0)" ::: "memory"); }
    __builtin_amdgcn_s_barrier();
    short8 af[4], bf[4];
    #pragma unroll
    for (int i=0;i<4;++i)
      af[i] = *(const short8*)(As[cur] + (wm*64 + i*16 + lr)*32 + (lk ^ ((lr>>1)&3))*8);
    #pragma unroll
    for (int j=0;j<4;++j)
      bf[j] = *(const short8*)(Bs[cur] + (wn*64 + j*16 + lr)*32 + (lk ^ ((lr>>1)&3))*8);
    __builtin_amdgcn_s_setprio(1);
    #pragma unroll
    for (int i=0;i<4;++i){
      #pragma unroll
      for (int j=0;j<4;++j)
        acc[i][j] = __builtin_amdgcn_mfma_f32_16x16x32_bf16(af[i], bf[j], acc[i][j], 0, 0, 0);
    }
    __builtin_amdgcn_s_setprio(0);
    __builtin_amdgcn_s_barrier();
    cur = cur + 1; if (cur > 2) cur = 0;
  }

  #pragma unroll
  for (int i=0;i<4;++i){
    #pragma unroll
    for (int j=0;j<4;++j){
      int n = bn0 + wn*64 + j*16 + lr;
      float bn_ = bias[(size_t)e*N + n];
      #pragma unroll
      for (int r=0;r<4;++r){
        int mloc = wm*64 + i*16 + lk*4 + r;
        int mg = bm0 + mloc;
        if ((uint)mg < scnt){
          int tok = ids1[e*CH + mg];
          float g = gates[(size_t)tok*NE + e];
          atomicAdd(&resid[(size_t)tok*N + n], g*(acc[i][j][r] + bn_));
        }
      }
    }
  }
}

// ---------- final: LN(resid) -> LN -> @w_cls + b_cls (4 tokens/block) ----------
__global__ __launch_bounds__(256) void final_kernel(
    const float* __restrict__ resid,
    const float* __restrict__ g_moe, const float* __restrict__ beta_moe,
    const float* __restrict__ g_out, const float* __restrict__ beta_out,
    const float* __restrict__ w_cls, const float* __restrict__ b_cls,
    float* __restrict__ out)
{
  int tok = blockIdx.x*4 + (threadIdx.x>>6);
  int l = threadIdx.x & 63;
  const float* row = resid + (size_t)tok*DM;
  float u[16];
  double s=0.0,q=0.0;
  #pragma unroll
  for (int r=0;r<16;++r){ u[r]=row[l + 64*r]; s+=u[r]; q+=(double)u[r]*u[r]; }
  s=wredd(s); q=wredd(q);
  double m1 = s*(1.0/1024.0), v1 = q*(1.0/1024.0)-m1*m1;
  double rs1 = 1.0/sqrt(v1+1e-5);
  float tv[16]; double s2=0.0,q2=0.0;
  #pragma unroll
  for (int r=0;r<16;++r){
    int j = l+64*r;
    float vv = (float)((u[r]-m1)*rs1)*g_moe[j] + beta_moe[j];
    tv[r]=vv; s2+=vv; q2+=(double)vv*vv;
  }
  s2=wredd(s2); q2=wredd(q2);
  double m2=s2*(1.0/1024.0), v2=q2*(1.0/1024.0)-m2*m2;
  double rs2=1.0/sqrt(v2+1e-5);
  double p0=0.0,p1=0.0;
  #pragma unroll
  for (int r=0;r<16;++r){
    int j=l+64*r;
    double y=((double)tv[r]-m2)*rs2*(double)g_out[j]+(double)beta_out[j];
    p0+=y*(double)w_cls[j*2]; p1+=y*(double)w_cls[j*2+1];
  }
  p0=wredd(p0); p1=wredd(p1);
  if (l==0){
    out[(size_t)tok*2  ]=(float)(p0+(double)b_cls[0]);
    out[(size_t)tok*2+1]=(float)(p1+(double)b_cls[1]);
  }
}

extern "C" void kernel_launch(void* const* d_in, const int* in_sizes, int n_in,
                              void* d_out, int out_size, void* d_ws, size_t ws_size,
                              hipStream_t stream)
{
  (void)in_sizes; (void)n_in; (void)out_size;
  const float* x       = (const float*)d_in[0];
  const float* w_in    = (const float*)d_in[1];
  const float* b_in    = (const float*)d_in[2];
  const float* g_in    = (const float*)d_in[3];
  const float* beta_in = (const float*)d_in[4];
  const float* w_gate  = (const float*)d_in[5];
  const float* w1      = (const float*)d_in[6];
  const float* b1      = (const float*)d_in[7];
  const float* w2      = (const float*)d_in[8];
  const float* b2      = (const float*)d_in[9];
  const float* g_moe   = (const float*)d_in[10];
  const float* beta_mo = (const float*)d_in[11];
  const float* g_out   = (const float*)d_in[12];
  const float* beta_ou = (const float*)d_in[13];
  const float* w_cls   = (const float*)d_in[14];
  const float* b_cls   = (const float*)d_in[15];
  float* out = (float*)d_out;

  // ---- workspace carve ----
  char* p = (char*)d_ws;
  ushort* w1t   = (ushort*)p; p += (size_t)NE*HD*DM*2;
  ushort* w2t   = (ushort*)p; p += (size_t)NE*DM*HD*2;
  ushort* hbf   = (ushort*)p; p += (size_t)NTOK*DM*2;
  float*  resid = (float*)p;  p += (size_t)NTOK*DM*4;      // also router-GEMM y
  float*  gates = (float*)p;  p += (size_t)NTOK*NE*4;
  int*    selmk = (int*)p;    p += (size_t)NTOK*4;
  int*    ids1  = (int*)p;    p += (size_t)NE*NTOK*4;
  ushort* wt3   = (ushort*)p; p += (size_t)DM*768*2;
  float*  wgt   = (float*)p;  p += (size_t)NE*DM*4;
  uint*   bc1   = (uint*)p;   p += (size_t)64*8*4;
  uint*   bc2   = (uint*)p;   p += (size_t)64*16*4;
  uint*   meta  = (uint*)p;   p += (size_t)MT_TOTAL*4;
  size_t fixed = (size_t)(p - (char*)d_ws);

  const size_t xs3_bytes = (size_t)NTOK*768*2;             // 25.2 MB
  size_t t1b1 = ((size_t)2*NTOK        + 2048)*HD*2;       // 138.5 MB
  size_t t1b2 = ((size_t)2*(NTOK/2)    + 2048)*HD*2;
  size_t t1b4 = ((size_t)2*(NTOK/4)    + 2048)*HD*2;
  int nch = 8;
  if      (ws_size >= fixed + (t1b1 > xs3_bytes ? t1b1 : xs3_bytes)) nch = 1;
  else if (ws_size >= fixed + (t1b2 > xs3_bytes ? t1b2 : xs3_bytes)) nch = 2;
  else if (ws_size >= fixed + (t1b4 > xs3_bytes ? t1b4 : xs3_bytes)) nch = 4;
  const int CH  = NTOK/nch;
  const int TPC = CH/256;
  ushort* t1  = (ushort*)p;
  ushort* xs3 = (ushort*)p;       // aliases t1 (dead before t1 written)

  // ---- router path (bf16x3 MFMA emulated-f32) ----
  split_x_kernel<<<dim3(NTOK*D_IN/4/256), 256, 0, stream>>>(x, xs3);
  transpose_split3_kernel<<<dim3(DM/32, D_IN/32), 256, 0, stream>>>(w_in, wt3);
  wgate_t_kernel<<<dim3(NE), 256, 0, stream>>>(w_gate, wgt);
  transpose_both_kernel<<<dim3(32768), 256, 0, stream>>>(w1, w2, w1t, w2t);

  gemm_router<<<dim3(DM/128, NTOK/128), 256, 0, stream>>>(xs3, wt3, b_in, resid);
  ln_router_kernel<<<dim3(NTOK/4), 256, 0, stream>>>(g_in, beta_in, wgt,
                                                     hbf, resid, gates, selmk);

  hipMemsetAsync(ids1, 0, (size_t)NE*NTOK*4, stream);

  builder_count<<<dim3(NTOK/256), 256, 0, stream>>>(selmk, bc1, bc2);
  builder_scan<<<dim3(1), 256, 0, stream>>>(bc1, bc2, meta, nch, TPC);
  builder_fill<<<dim3(NTOK/256), 256, 0, stream>>>(selmk, meta, ids1, CH);

  for (int c = 0; c < nch; ++c) {
    gemm_ffn1<<<dim3(HD/128, CH/128, NE), 256, 0, stream>>>(
        hbf, w1t, ids1 + (size_t)c*8*CH,
        meta+MT_P1+c*8, meta+MT_OFF1+c*8, b1, t1, DM, HD, CH);
    gemm_ffn2<<<dim3(DM/128, CH/128, NE), 256, 0, stream>>>(
        t1, w2t, ids1 + (size_t)c*8*CH,
        meta+MT_CNT1+c*8, meta+MT_P1+c*8, meta+MT_OFF1+c*8,
        b2, gates, resid, HD, DM, CH);
  }

  final_kernel<<<dim3(NTOK/4), 256, 0, stream>>>(resid, g_moe, beta_mo, g_out, beta_ou,
                                                 w_cls, b_cls, out);
}

// Round 15
// 806.949 us; speedup vs baseline: 1.1202x; 1.1042x over previous
//
#include <hip/hip_runtime.h>
#include <hip/hip_bf16.h>

#define D_IN 256
#define DM   1024
#define HD   2048
#define NE   8
#define NTOK 16384

typedef __attribute__((ext_vector_type(8))) short short8;
typedef __attribute__((ext_vector_type(4))) float f32x4;
typedef unsigned int uint;

// ---- meta layout (uint indices) ----
#define MT_TOFF1 0      // [64][8]
#define MT_TOFF2 512    // [64][16]
#define MT_CNT1  1536   // [8][8]
#define MT_P1    1600   // [8][8]    roundup128(cnt1)
#define MT_OFF1  1664   // [8][8]
#define MT_CNT2  1728   // [8][16]
#define MT_PCNT2 1856   // [8][16]
#define MT_TOTAL 1984

__device__ inline ushort f2bf(float v){
  __hip_bfloat16 b = __float2bfloat16(v);
  return *reinterpret_cast<ushort*>(&b);
}
__device__ inline float bf2f(ushort u){
  __hip_bfloat16 b = *reinterpret_cast<__hip_bfloat16*>(&u);
  return __bfloat162float(b);
}

// gelu tanh-approx via identity 0.5*(1+tanh(u)) = sigmoid(2u)
__device__ inline float gelu_fast(float x){
  float u = 0.7978845608028654f * x * (1.0f + 0.044715f*x*x);
  return x / (1.0f + __expf(-2.0f*u));
}

__device__ inline void gload16(const void* g, void* l){
  __builtin_amdgcn_global_load_lds(
      (const __attribute__((address_space(1))) void*)g,
      (__attribute__((address_space(3))) void*)l, 16, 0, 0);
}

// LDS bank swizzle (both sides, involution): chunk c (16B) of row r stored at
// position c ^ ((r>>1)&3); stage sources the inverse-permuted global chunk so
// gload_lds dests stay linear. Verified: conflicts=0 (r11).

// ---------- fused transpose [R][C] f32 -> [C][R] bf16 for w1 AND w2 ----------
__global__ __launch_bounds__(256) void transpose_both_kernel(
    const float* __restrict__ w1, const float* __restrict__ w2,
    ushort* __restrict__ w1t, ushort* __restrict__ w2t)
{
  __shared__ float tile[32][33];
  int bid = blockIdx.x;                 // 0..32767
  int which = bid >> 14;
  int r = bid & 16383;
  const float* src; ushort* dst; int R, C;
  if (which==0){ src=w1; dst=w1t; R=DM; C=HD; }
  else         { src=w2; dst=w2t; R=HD; C=DM; }
  int nbx = C/32, nby = R/32;
  int e = r / (nbx*nby); int rem = r % (nbx*nby);
  int c0 = (rem % nbx)*32, r0 = (rem / nbx)*32;
  src += (size_t)e*R*C; dst += (size_t)e*R*C;
  int tx = threadIdx.x & 31, ty = threadIdx.x >> 5;
  #pragma unroll
  for (int rr = ty; rr < 32; rr += 8)
    tile[rr][tx] = src[(size_t)(r0+rr)*C + c0+tx];
  __syncthreads();
  #pragma unroll
  for (int rr = ty; rr < 32; rr += 8)
    dst[(size_t)(c0+rr)*R + r0+tx] = f2bf(tile[tx][rr]);
}

// ---------- split x[N][256] f32 -> xs3[N][768] bf16 (hi|mid|lo 256-blocks) ----------
__global__ __launch_bounds__(256) void split_x_kernel(
    const float* __restrict__ x, ushort* __restrict__ xs3)
{
  int g = blockIdx.x*256 + threadIdx.x;
  int e0 = g*4;
  int row = e0 >> 8, col = e0 & 255;
  f32x4 v = *(const f32x4*)(x + (size_t)row*D_IN + col);
  ushort4 hi, mi, lo;
  #pragma unroll
  for (int i=0;i<4;++i){
    float f = v[i];
    ushort h = f2bf(f);       float fh = bf2f(h);
    ushort m = f2bf(f - fh);  float fm = bf2f(m);
    ushort l = f2bf(f - fh - fm);
    ((ushort*)&hi)[i]=h; ((ushort*)&mi)[i]=m; ((ushort*)&lo)[i]=l;
  }
  ushort* base = xs3 + (size_t)row*768 + col;
  *(ushort4*)(base)       = hi;
  *(ushort4*)(base + 256) = mi;
  *(ushort4*)(base + 512) = lo;
}

// ---------- transpose+split w_in[256][1024] f32 -> wt3[1024][768] bf16 ----------
__global__ __launch_bounds__(256) void transpose_split3_kernel(
    const float* __restrict__ src, ushort* __restrict__ dst)
{
  __shared__ float tile[32][33];
  int c0 = blockIdx.x*32, r0 = blockIdx.y*32;
  int tx = threadIdx.x & 31, ty = threadIdx.x >> 5;
  #pragma unroll
  for (int rr = ty; rr < 32; rr += 8)
    tile[rr][tx] = src[(size_t)(r0+rr)*DM + c0+tx];
  __syncthreads();
  #pragma unroll
  for (int rr = ty; rr < 32; rr += 8){
    float f = tile[tx][rr];
    ushort h = f2bf(f);       float fh = bf2f(h);
    ushort m = f2bf(f - fh);  float fm = bf2f(m);
    ushort l = f2bf(f - fh - fm);
    ushort* d = dst + (size_t)(c0+rr)*768 + r0 + tx;
    d[0]   = h;
    d[256] = m;
    d[512] = l;
  }
}

// ---------- w_gate[1024][8] -> wgt[8][1024] ----------
__global__ __launch_bounds__(256) void wgate_t_kernel(
    const float* __restrict__ w_gate, float* __restrict__ wgt)
{
  int e = blockIdx.x;
  for (int j = threadIdx.x; j < DM; j += 256)
    wgt[(size_t)e*DM + j] = w_gate[(size_t)j*NE + e];
}

// ---------- router GEMM: y = x @ w_in + b_in via bf16x3 (6 terms, K=6*256) ----------
__global__ __launch_bounds__(256) void gemm_router(
    const ushort* __restrict__ A,    // [NTOK][768]
    const ushort* __restrict__ BT,   // [DM][768]
    const float* __restrict__ b_in,
    float* __restrict__ y)           // [NTOK][DM]
{
  __shared__ ushort As[3][128*32];
  __shared__ ushort Bs[3][128*32];
  const int tid = threadIdx.x;
  const int w = tid>>6, l = tid&63;
  const int wm = w>>1, wn = w&1;
  const int bm0 = blockIdx.y*128, bn0 = blockIdx.x*128;
  const int lr = l&15, lk = l>>4;
  const int rsub = l>>2;
  const int csub = ((l&3) ^ ((l>>3)&3)) * 8;

  const ushort* ag[2]; const ushort* bg[2];
  int aslot[2];
  #pragma unroll
  for (int i=0;i<2;++i){
    int ra = bm0 + w*32 + i*16 + rsub;
    int rb = bn0 + w*32 + i*16 + rsub;
    ag[i] = A  + (size_t)ra*768 + csub;
    bg[i] = BT + (size_t)rb*768 + csub;
    aslot[i] = (w*32 + i*16)*32;
  }

  const int pOffT[6] = {0,256,0,256,512,0};
  const int qOffT[6] = {0,0,256,256,0,512};
  auto stage = [&](int db, int t){
    int pOff = pOffT[t>>3] + (t&7)*32;
    int qOff = qOffT[t>>3] + (t&7)*32;
    #pragma unroll
    for (int i=0;i<2;++i){
      gload16(ag[i]+pOff, (ushort*)As[db] + aslot[i]);
      gload16(bg[i]+qOff, (ushort*)Bs[db] + aslot[i]);
    }
  };

  f32x4 acc[4][4] = {};
  const int NK = 48;
  stage(0, 0); stage(1, 1);
  int cur = 0;
  for (int t=0; t<NK; ++t){
    int sb = cur - 1; if (sb < 0) sb = 2;
    if (t+2 < NK)     { stage(sb, t+2); asm volatile("s_waitcnt vmcnt(8)" ::: "memory"); }
    else if (t+1 < NK){                 asm volatile("s_waitcnt vmcnt(4)" ::: "memory"); }
    else              {                 asm volatile("s_waitcnt vmcnt(0)" ::: "memory"); }
    __builtin_amdgcn_s_barrier();
    short8 af[4], bf[4];
    #pragma unroll
    for (int i=0;i<4;++i)
      af[i] = *(const short8*)(As[cur] + (wm*64 + i*16 + lr)*32 + (lk ^ ((lr>>1)&3))*8);
    #pragma unroll
    for (int j=0;j<4;++j)
      bf[j] = *(const short8*)(Bs[cur] + (wn*64 + j*16 + lr)*32 + (lk ^ ((lr>>1)&3))*8);
    __builtin_amdgcn_s_setprio(1);
    #pragma unroll
    for (int i=0;i<4;++i){
      #pragma unroll
      for (int j=0;j<4;++j)
        acc[i][j] = __builtin_amdgcn_mfma_f32_16x16x32_bf16(af[i], bf[j], acc[i][j], 0, 0, 0);
    }
    __builtin_amdgcn_s_setprio(0);
    __builtin_amdgcn_s_barrier();
    cur = cur + 1; if (cur > 2) cur = 0;
  }

  #pragma unroll
  for (int i=0;i<4;++i){
    #pragma unroll
    for (int j=0;j<4;++j){
      int n = bn0 + wn*64 + j*16 + lr;
      float bn_ = b_in[n];
      #pragma unroll
      for (int r=0;r<4;++r){
        int m = bm0 + wm*64 + i*16 + lk*4 + r;
        y[(size_t)m*DM + n] = acc[i][j][r] + bn_;
      }
    }
  }
}

// ---------- LN + logits + softmax top2 (wave per token); writes hbf only ----------
__device__ inline double wredd(double v){
  #pragma unroll
  for (int o=32;o>0;o>>=1) v += __shfl_xor(v, o, 64);
  return v;
}

__global__ __launch_bounds__(256) void ln_router_kernel(
    const float* __restrict__ g_in, const float* __restrict__ beta_in,
    const float* __restrict__ wgt,
    const float* __restrict__ y,
    ushort* __restrict__ hbf,
    float* __restrict__ gates, int* __restrict__ selmask)
{
  int tok = blockIdx.x*4 + (threadIdx.x>>6);
  int l = threadIdx.x & 63;
  const float* row = y + (size_t)tok*DM;
  float u[16];
  double s=0.0, q=0.0;
  #pragma unroll
  for (int r=0;r<16;++r){ u[r]=row[l+64*r]; s+=u[r]; q+=(double)u[r]*u[r]; }
  s = wredd(s); q = wredd(q);
  double mean = s*(1.0/1024.0);
  double var  = q*(1.0/1024.0) - mean*mean;
  double rstd = 1.0/sqrt(var + 1e-5);

  double lg[NE];
  #pragma unroll
  for (int e=0;e<NE;++e) lg[e]=0.0;
  float hv[16];
  #pragma unroll
  for (int r=0;r<16;++r){
    int j = l + 64*r;
    double v = ((double)u[r]-mean)*rstd*(double)g_in[j] + (double)beta_in[j];
    hv[r] = (float)v;
    #pragma unroll
    for (int e=0;e<NE;++e) lg[e] += v*(double)wgt[(size_t)e*DM + j];
  }
  #pragma unroll
  for (int r=0;r<16;++r){
    int j = l + 64*r;
    hbf[(size_t)tok*DM + j] = f2bf(hv[r]);
  }
  #pragma unroll
  for (int e=0;e<NE;++e) lg[e] = wredd(lg[e]);

  if (l==0){
    double mx = lg[0];
    #pragma unroll
    for (int e=1;e<NE;++e) mx = lg[e]>mx ? lg[e] : mx;
    double p[NE]; double sum=0.0;
    #pragma unroll
    for (int e=0;e<NE;++e){ p[e]=exp(lg[e]-mx); sum+=p[e]; }
    #pragma unroll
    for (int e=0;e<NE;++e) p[e]/=sum;
    int i1=0;
    for (int e=1;e<NE;++e) if (p[e]>p[i1]) i1=e;
    int i2=-1;
    for (int e=0;e<NE;++e){ if (e==i1) continue; if (i2<0 || p[e]>p[i2]) i2=e; }
    double denom = p[i1]+p[i2]+1e-9;
    float g[NE];
    #pragma unroll
    for (int e=0;e<NE;++e) g[e]=0.f;
    g[i1]=(float)(p[i1]/denom);
    g[i2]=(float)(p[i2]/denom);
    #pragma unroll
    for (int e=0;e<NE;++e) gates[(size_t)tok*NE+e]=g[e];
    selmask[tok] = (1<<i1)|(1<<i2);
  }
}

// ---------- builders ----------
__global__ __launch_bounds__(256) void builder_count(
    const int* __restrict__ selmask, uint* __restrict__ bc1, uint* __restrict__ bc2)
{
  __shared__ uint c1[8], c2s[16];
  int b = blockIdx.x, tid = threadIdx.x;
  if (tid<8) c1[tid]=0;
  if (tid<16) c2s[tid]=0;
  __syncthreads();
  int m = selmask[b*256+tid];
  int ea = __ffs(m)-1, eb = 31-__clz(m);
  atomicAdd(&c1[ea],1u); atomicAdd(&c1[eb],1u);
  atomicAdd(&c2s[ea],1u); atomicAdd(&c2s[8+eb],1u);
  __syncthreads();
  if (tid<8) bc1[b*8+tid]=c1[tid];
  if (tid<16) bc2[b*16+tid]=c2s[tid];
}

__global__ __launch_bounds__(256) void builder_scan(
    const uint* __restrict__ bc1, const uint* __restrict__ bc2,
    uint* __restrict__ meta, int nch, int TPC)
{
  int tid = threadIdx.x;
  int c = tid/24, k = tid%24;
  if (c < nch){
    if (k < 8){
      uint run=0;
      for (int b=c*TPC; b<(c+1)*TPC; ++b){ meta[MT_TOFF1 + b*8 + k] = run; run += bc1[b*8+k]; }
      meta[MT_CNT1 + c*8 + k] = run;
    } else {
      int k2 = k-8;
      uint run=0;
      for (int b=c*TPC; b<(c+1)*TPC; ++b){ meta[MT_TOFF2 + b*16 + k2] = run; run += bc2[b*16+k2]; }
      meta[MT_CNT2 + c*16 + k2] = run;
      meta[MT_PCNT2 + c*16 + k2] = ((run + 127u)/128u)*128u;
    }
  }
  __syncthreads();
  if (tid < nch){
    uint off=0;
    for (int e=0;e<8;++e){
      uint cn = meta[MT_CNT1 + tid*8 + e];
      uint p = ((cn+127u)/128u)*128u;
      meta[MT_P1 + tid*8 + e] = p;
      meta[MT_OFF1 + tid*8 + e] = off;
      off += p;
    }
  }
}

__device__ inline int exclscan256(int v, int* sc, int tid){
  sc[tid]=v; __syncthreads();
  #pragma unroll
  for (int o=1;o<256;o<<=1){
    int x = (tid>=o) ? sc[tid-o] : 0;
    __syncthreads();
    sc[tid]+=x;
    __syncthreads();
  }
  int incl = sc[tid]; __syncthreads();
  return incl - v;
}

// L1 list per (chunk, expert): slot0 tokens first, then slot1.
// Also emits rowmap[2*tok+slot] = global eo row = c*EOC + off1[e] + pos.
__global__ __launch_bounds__(256) void builder_fill(
    const int* __restrict__ selmask, const uint* __restrict__ meta,
    int* __restrict__ ids1, int* __restrict__ rowmap, int CH, int EOC)
{
  __shared__ int sc[256];
  int b = blockIdx.x, tid = threadIdx.x;
  int t = b*256 + tid;
  int c = t / CH;
  int m = selmask[t];
  int ea = __ffs(m)-1, eb = 31-__clz(m);
  int ja=0, jb=0;
  for (int e=0;e<8;++e){
    int r0 = exclscan256((ea==e)?1:0, sc, tid);
    if (ea==e) ja = r0;
    int r1 = exclscan256((eb==e)?1:0, sc, tid);
    if (eb==e) jb = r1;
  }
  {
    uint j   = meta[MT_TOFF2 + b*16 + ea] + (uint)ja;        // slot0 position
    ids1[(c*8+ea)*CH + j] = t;
    rowmap[2*t+0] = c*EOC + (int)meta[MT_OFF1 + c*8 + ea] + (int)j;
  }
  {
    uint j    = meta[MT_TOFF2 + b*16 + 8 + eb] + (uint)jb;   // slot1 position
    uint pos1 = meta[MT_CNT2 + c*16 + eb] + j;
    ids1[(c*8+eb)*CH + pos1] = t;
    rowmap[2*t+1] = c*EOC + (int)meta[MT_OFF1 + c*8 + eb] + (int)pos1;
  }
}

// ---------- FFN-1: sparse gather-GEMM, m97 128^2 + 3-deep dbuf + swizzle ----------
__global__ __launch_bounds__(256) void gemm_ffn1(
    const ushort* __restrict__ Abase,   // hbf
    const ushort* __restrict__ BT,      // w1t [E][HD][DM]
    const int*   __restrict__ rows,     // ids1 + c*8*CH
    const uint*  __restrict__ pcnt,     // P1
    const uint*  __restrict__ off1,
    const float* __restrict__ bias,     // b1
    ushort* __restrict__ t1,
    int K, int N, int CH)
{
  const int e = blockIdx.z;
  const int bm0 = blockIdx.y*128;
  if ((uint)bm0 >= pcnt[e]) return;
  const int bn0 = blockIdx.x*128;

  __shared__ ushort As[3][128*32];
  __shared__ ushort Bs[3][128*32];
  const int tid = threadIdx.x;
  const int w = tid>>6, l = tid&63;
  const int wm = w>>1, wn = w&1;
  const int lr = l&15, lk = l>>4;
  const int rsub = l>>2;
  const int csub = ((l&3) ^ ((l>>3)&3)) * 8;

  const ushort* ag[2]; const ushort* bg[2];
  int slot[2];
  #pragma unroll
  for (int i=0;i<2;++i){
    int ra = w*32 + i*16 + rsub;
    int id = rows[e*CH + bm0 + ra];
    ag[i] = Abase + (size_t)id*K + csub;
    int rb = bn0 + w*32 + i*16 + rsub;
    bg[i] = BT + (size_t)e*N*K + (size_t)rb*K + csub;
    slot[i] = (w*32 + i*16)*32;
  }

  auto stage = [&](int db, int kt){
    #pragma unroll
    for (int i=0;i<2;++i){
      gload16(ag[i]+kt, (ushort*)As[db] + slot[i]);
      gload16(bg[i]+kt, (ushort*)Bs[db] + slot[i]);
    }
  };

  f32x4 acc[4][4] = {};
  const int NK = K>>5;
  stage(0, 0); stage(1, 32);
  int cur = 0;
  for (int t=0; t<NK; ++t){
    int sb = cur - 1; if (sb < 0) sb = 2;
    if (t+2 < NK)     { stage(sb, (t+2)<<5); asm volatile("s_waitcnt vmcnt(8)" ::: "memory"); }
    else if (t+1 < NK){                      asm volatile("s_waitcnt vmcnt(4)" ::: "memory"); }
    else              {                      asm volatile("s_waitcnt vmcnt(0)" ::: "memory"); }
    __builtin_amdgcn_s_barrier();
    short8 af[4], bf[4];
    #pragma unroll
    for (int i=0;i<4;++i)
      af[i] = *(const short8*)(As[cur] + (wm*64 + i*16 + lr)*32 + (lk ^ ((lr>>1)&3))*8);
    #pragma unroll
    for (int j=0;j<4;++j)
      bf[j] = *(const short8*)(Bs[cur] + (wn*64 + j*16 + lr)*32 + (lk ^ ((lr>>1)&3))*8);
    __builtin_amdgcn_s_setprio(1);
    #pragma unroll
    for (int i=0;i<4;++i){
      #pragma unroll
      for (int j=0;j<4;++j)
        acc[i][j] = __builtin_amdgcn_mfma_f32_16x16x32_bf16(af[i], bf[j], acc[i][j], 0, 0, 0);
    }
    __builtin_amdgcn_s_setprio(0);
    __builtin_amdgcn_s_barrier();
    cur = cur + 1; if (cur > 2) cur = 0;
  }

  #pragma unroll
  for (int i=0;i<4;++i){
    #pragma unroll
    for (int j=0;j<4;++j){
      int n = bn0 + wn*64 + j*16 + lr;
      float bn_ = bias[(size_t)e*N + n];
      #pragma unroll
      for (int r=0;r<4;++r){
        int mloc = wm*64 + i*16 + lk*4 + r;
        float v = acc[i][j][r] + bn_;
        size_t trow = (size_t)off1[e] + bm0 + mloc;
        t1[trow*N + n] = f2bf(gelu_fast(v));
      }
    }
  }
}

// ---------- FFN-2: dense-A GEMM, WRITE-ONLY epilogue: eo[row] = bf16(g*(v+b2)) ----------
// No scatter, no RMW, no atomics. eo row = cbase + off1[e] + bm0 + mloc (same
// indexing as t1). final_kernel composes h + eo[r0] + eo[r1] via rowmap.
__global__ __launch_bounds__(256) void gemm_ffn2(
    const ushort* __restrict__ t1,
    const ushort* __restrict__ BT,      // w2t [E][DM][HD]
    const int*   __restrict__ ids1,     // + c*8*CH
    const uint*  __restrict__ cnt1,     // [8]
    const uint*  __restrict__ pcnt1,    // [8]
    const uint*  __restrict__ off1,
    const float* __restrict__ bias,     // b2
    const float* __restrict__ gates,
    ushort* __restrict__ eo,
    int cbase,
    int K, int N, int CH)
{
  const int e = blockIdx.z;
  const int bm0 = blockIdx.y*128;
  if ((uint)bm0 >= pcnt1[e]) return;
  const uint scnt = cnt1[e];
  const int bn0 = blockIdx.x*128;

  __shared__ ushort As[3][128*32];
  __shared__ ushort Bs[3][128*32];
  const int tid = threadIdx.x;
  const int w = tid>>6, l = tid&63;
  const int wm = w>>1, wn = w&1;
  const int lr = l&15, lk = l>>4;
  const int rsub = l>>2;
  const int csub = ((l&3) ^ ((l>>3)&3)) * 8;

  const ushort* ag[2]; const ushort* bg[2];
  int slot[2];
  #pragma unroll
  for (int i=0;i<2;++i){
    int ra = w*32 + i*16 + rsub;
    size_t arow = (size_t)off1[e] + bm0 + ra;   // dense rows 0..cnt1
    ag[i] = t1 + arow*K + csub;
    int rb = bn0 + w*32 + i*16 + rsub;
    bg[i] = BT + (size_t)e*N*K + (size_t)rb*K + csub;
    slot[i] = (w*32 + i*16)*32;
  }

  auto stage = [&](int db, int kt){
    #pragma unroll
    for (int i=0;i<2;++i){
      gload16(ag[i]+kt, (ushort*)As[db] + slot[i]);
      gload16(bg[i]+kt, (ushort*)Bs[db] + slot[i]);
    }
  };

  f32x4 acc[4][4] = {};
  const int NK = K>>5;
  stage(0, 0); stage(1, 32);
  int cur = 0;
  for (int t=0; t<NK; ++t){
    int sb = cur - 1; if (sb < 0) sb = 2;
    if (t+2 < NK)     { stage(sb, (t+2)<<5); asm volatile("s_waitcnt vmcnt(8)" ::: "memory"); }
    else if (t+1 < NK){                      asm volatile("s_waitcnt vmcnt(4)" ::: "memory"); }
    else              {                      asm volatile("s_waitcnt vmcnt(0)" ::: "memory"); }
    __builtin_amdgcn_s_barrier();
    short8 af[4], bf[4];
    #pragma unroll
    for (int i=0;i<4;++i)
      af[i] = *(const short8*)(As[cur] + (wm*64 + i*16 + lr)*32 + (lk ^ ((lr>>1)&3))*8);
    #pragma unroll
    for (int j=0;j<4;++j)
      bf[j] = *(const short8*)(Bs[cur] + (wn*64 + j*16 + lr)*32 + (lk ^ ((lr>>1)&3))*8);
    __builtin_amdgcn_s_setprio(1);
    #pragma unroll
    for (int i=0;i<4;++i){
      #pragma unroll
      for (int j=0;j<4;++j)
        acc[i][j] = __builtin_amdgcn_mfma_f32_16x16x32_bf16(af[i], bf[j], acc[i][j], 0, 0, 0);
    }
    __builtin_amdgcn_s_setprio(0);
    __builtin_amdgcn_s_barrier();
    cur = cur + 1; if (cur > 2) cur = 0;
  }

  #pragma unroll
  for (int i=0;i<4;++i){
    #pragma unroll
    for (int j=0;j<4;++j){
      int n = bn0 + wn*64 + j*16 + lr;
      float bn_ = bias[(size_t)e*N + n];
      #pragma unroll
      for (int r=0;r<4;++r){
        int mloc = wm*64 + i*16 + lk*4 + r;
        int mg = bm0 + mloc;
        if ((uint)mg < scnt){
          int tok = ids1[e*CH + mg];
          float g = gates[(size_t)tok*NE + e];
          size_t erow = (size_t)cbase + off1[e] + mg;
          eo[erow*N + n] = f2bf(g*(acc[i][j][r] + bn_));
        }
      }
    }
  }
}

// ---------- final: (h + eo[r0] + eo[r1]) -> LN -> LN -> @w_cls + b_cls ----------
__global__ __launch_bounds__(256) void final_kernel(
    const ushort* __restrict__ hbf,
    const ushort* __restrict__ eo,
    const int* __restrict__ rowmap,
    const float* __restrict__ g_moe, const float* __restrict__ beta_moe,
    const float* __restrict__ g_out, const float* __restrict__ beta_out,
    const float* __restrict__ w_cls, const float* __restrict__ b_cls,
    float* __restrict__ out)
{
  int tok = blockIdx.x*4 + (threadIdx.x>>6);
  int l = threadIdx.x & 63;
  const ushort* hr  = hbf + (size_t)tok*DM;
  const ushort* er0 = eo + (size_t)rowmap[2*tok  ]*DM;
  const ushort* er1 = eo + (size_t)rowmap[2*tok+1]*DM;
  float u[16];
  double s=0.0,q=0.0;
  #pragma unroll
  for (int r=0;r<16;++r){
    int j = l + 64*r;
    float v = bf2f(hr[j]) + bf2f(er0[j]) + bf2f(er1[j]);
    u[r]=v; s+=v; q+=(double)v*v;
  }
  s=wredd(s); q=wredd(q);
  double m1 = s*(1.0/1024.0), v1 = q*(1.0/1024.0)-m1*m1;
  double rs1 = 1.0/sqrt(v1+1e-5);
  float tv[16]; double s2=0.0,q2=0.0;
  #pragma unroll
  for (int r=0;r<16;++r){
    int j = l+64*r;
    float vv = (float)((u[r]-m1)*rs1)*g_moe[j] + beta_moe[j];
    tv[r]=vv; s2+=vv; q2+=(double)vv*vv;
  }
  s2=wredd(s2); q2=wredd(q2);
  double m2=s2*(1.0/1024.0), v2=q2*(1.0/1024.0)-m2*m2;
  double rs2=1.0/sqrt(v2+1e-5);
  double p0=0.0,p1=0.0;
  #pragma unroll
  for (int r=0;r<16;++r){
    int j=l+64*r;
    double yv=((double)tv[r]-m2)*rs2*(double)g_out[j]+(double)beta_out[j];
    p0+=yv*(double)w_cls[j*2]; p1+=yv*(double)w_cls[j*2+1];
  }
  p0=wredd(p0); p1=wredd(p1);
  if (l==0){
    out[(size_t)tok*2  ]=(float)(p0+(double)b_cls[0]);
    out[(size_t)tok*2+1]=(float)(p1+(double)b_cls[1]);
  }
}

extern "C" void kernel_launch(void* const* d_in, const int* in_sizes, int n_in,
                              void* d_out, int out_size, void* d_ws, size_t ws_size,
                              hipStream_t stream)
{
  (void)in_sizes; (void)n_in; (void)out_size;
  const float* x       = (const float*)d_in[0];
  const float* w_in    = (const float*)d_in[1];
  const float* b_in    = (const float*)d_in[2];
  const float* g_in    = (const float*)d_in[3];
  const float* beta_in = (const float*)d_in[4];
  const float* w_gate  = (const float*)d_in[5];
  const float* w1      = (const float*)d_in[6];
  const float* b1      = (const float*)d_in[7];
  const float* w2      = (const float*)d_in[8];
  const float* b2      = (const float*)d_in[9];
  const float* g_moe   = (const float*)d_in[10];
  const float* beta_mo = (const float*)d_in[11];
  const float* g_out   = (const float*)d_in[12];
  const float* beta_ou = (const float*)d_in[13];
  const float* w_cls   = (const float*)d_in[14];
  const float* b_cls   = (const float*)d_in[15];
  float* out = (float*)d_out;

  // ---- workspace carve ----
  char* p = (char*)d_ws;
  ushort* w1t   = (ushort*)p; p += (size_t)NE*HD*DM*2;
  ushort* w2t   = (ushort*)p; p += (size_t)NE*DM*HD*2;
  ushort* hbf   = (ushort*)p; p += (size_t)NTOK*DM*2;
  float*  gates = (float*)p;  p += (size_t)NTOK*NE*4;
  int*    selmk = (int*)p;    p += (size_t)NTOK*4;
  int*    ids1  = (int*)p;    p += (size_t)NE*NTOK*4;
  int*    rowmp = (int*)p;    p += (size_t)2*NTOK*4;
  ushort* wt3   = (ushort*)p; p += (size_t)DM*768*2;
  float*  wgt   = (float*)p;  p += (size_t)NE*DM*4;
  uint*   bc1   = (uint*)p;   p += (size_t)64*8*4;
  uint*   bc2   = (uint*)p;   p += (size_t)64*16*4;
  uint*   meta  = (uint*)p;   p += (size_t)MT_TOTAL*4;
  size_t base = (size_t)(p - (char*)d_ws);

  // yeo region: router-y (f32 NTOK*DM = 64 MiB) then reused as eo (bf16,
  // (2*NTOK + 1024*nch) rows x DM). t1/xs3 tail after it.
  const size_t y_bytes   = (size_t)NTOK*DM*4;
  const size_t xs3_bytes = (size_t)NTOK*768*2;
  int nch = 8;
  size_t yeo_bytes = 0, t1_bytes = 0;
  for (int cand = 1; cand <= 8; cand <<= 1){
    size_t eo_b = ((size_t)2*NTOK + 1024*(size_t)cand) * DM * 2;
    size_t ye   = eo_b > y_bytes ? eo_b : y_bytes;
    size_t t1b  = ((size_t)2*(NTOK/cand) + 2048) * HD * 2;
    size_t tail = t1b > xs3_bytes ? t1b : xs3_bytes;
    if (ws_size >= base + ye + tail){ nch = cand; yeo_bytes = ye; t1_bytes = t1b; break; }
  }
  if (yeo_bytes == 0){  // fallback (should not happen)
    nch = 8;
    size_t eo_b = ((size_t)2*NTOK + 1024*8) * DM * 2;
    yeo_bytes = eo_b > y_bytes ? eo_b : y_bytes;
  }
  const int CH  = NTOK/nch;
  const int TPC = CH/256;
  const int EOC = 2*CH + 1024;
  float*  y   = (float*)p;
  ushort* eo  = (ushort*)p;  p += yeo_bytes;
  ushort* t1  = (ushort*)p;
  ushort* xs3 = (ushort*)p;       // aliases t1 (dead before t1 written)

  // ---- router path (bf16x3 MFMA emulated-f32) ----
  split_x_kernel<<<dim3(NTOK*D_IN/4/256), 256, 0, stream>>>(x, xs3);
  transpose_split3_kernel<<<dim3(DM/32, D_IN/32), 256, 0, stream>>>(w_in, wt3);
  wgate_t_kernel<<<dim3(NE), 256, 0, stream>>>(w_gate, wgt);
  transpose_both_kernel<<<dim3(32768), 256, 0, stream>>>(w1, w2, w1t, w2t);

  gemm_router<<<dim3(DM/128, NTOK/128), 256, 0, stream>>>(xs3, wt3, b_in, y);
  ln_router_kernel<<<dim3(NTOK/4), 256, 0, stream>>>(g_in, beta_in, wgt, y,
                                                     hbf, gates, selmk);

  hipMemsetAsync(ids1, 0, (size_t)NE*NTOK*4, stream);

  builder_count<<<dim3(NTOK/256), 256, 0, stream>>>(selmk, bc1, bc2);
  builder_scan<<<dim3(1), 256, 0, stream>>>(bc1, bc2, meta, nch, TPC);
  builder_fill<<<dim3(NTOK/256), 256, 0, stream>>>(selmk, meta, ids1, rowmp, CH, EOC);

  for (int c = 0; c < nch; ++c) {
    gemm_ffn1<<<dim3(HD/128, CH/128, NE), 256, 0, stream>>>(
        hbf, w1t, ids1 + (size_t)c*8*CH,
        meta+MT_P1+c*8, meta+MT_OFF1+c*8, b1, t1, DM, HD, CH);
    gemm_ffn2<<<dim3(DM/128, CH/128, NE), 256, 0, stream>>>(
        t1, w2t, ids1 + (size_t)c*8*CH,
        meta+MT_CNT1+c*8, meta+MT_P1+c*8, meta+MT_OFF1+c*8,
        b2, gates, eo, c*EOC, HD, DM, CH);
  }

  final_kernel<<<dim3(NTOK/4), 256, 0, stream>>>(hbf, eo, rowmp,
                                                 g_moe, beta_mo, g_out, beta_ou,
                                                 w_cls, b_cls, out);
}